// Round 2
// baseline (913.281 us; speedup 1.0000x reference)
//
#include <hip/hip_runtime.h>
#include <stdint.h>

typedef unsigned short u16;
typedef unsigned int u32;

#define DD 128
#define CAP 96
#define WT_STRIDE 132   // u16 elems; 264B rows -> 8B-aligned uint2 reads

__device__ __forceinline__ float bflo(u32 u){ return __uint_as_float(u<<16); }
__device__ __forceinline__ float bfhi(u32 u){ return __uint_as_float(u & 0xffff0000u); }
__device__ __forceinline__ float bf2f(u16 u){ return __uint_as_float(((u32)u)<<16); }
__device__ __forceinline__ u16 f2bf(float f){
  u32 u = __float_as_uint(f);
  return (u16)((u + 0x7fffu + ((u>>16)&1u)) >> 16);   // RNE
}

// K1: H4 row = [h1 | h2 | ht1 | ht2] (bf16), hX = row @ (W or Wt). x2 not stored.
__global__ __launch_bounds__(256) void k1_gemm_h4(
    const float* __restrict__ x, const float* __restrict__ perb,
    const float* __restrict__ W, const float* __restrict__ Wt,
    u16* __restrict__ H4, int N)
{
  __shared__ __align__(16) u16 WTl[DD*WT_STRIDE];   // 33792 B
  __shared__ __align__(16) float xs1[16][DD];       // 8192 B
  __shared__ __align__(16) float xs2[16][DD];       // 8192 B
  const int tid = threadIdx.x;
  const int g = blockIdx.y;
  const float* __restrict__ Wg = g ? Wt : W;
  for (int i = tid; i < DD*DD; i += 256) {
    int k = i >> 7, d = i & 127;
    WTl[d*WT_STRIDE + k] = f2bf(Wg[i]);
  }
  const int r0 = blockIdx.x * 16;
  for (int idx = tid; idx < 16*DD; idx += 256) {
    int rr = idx >> 7, c = idx & 127;
    int r = r0 + rr;
    float a = 0.f, s = 0.f;
    if (r < N) {
      a = x[(size_t)r*DD + c];
      s = a + perb[(size_t)r*DD + c];
    }
    xs1[rr][c] = a;
    xs2[rr][c] = s;
  }
  __syncthreads();
  const int d = tid & 127;
  const int rh = tid >> 7;
  for (int rr = rh; rr < 16; rr += 2) {
    int r = r0 + rr;
    if (r >= N) continue;
    float acc1 = 0.f, acc2 = 0.f;
    #pragma unroll
    for (int k = 0; k < DD; k += 4) {
      float4 a1 = *(const float4*)&xs1[rr][k];
      float4 a2 = *(const float4*)&xs2[rr][k];
      uint2 wu = *(const uint2*)&WTl[d*WT_STRIDE + k];
      float w0 = bflo(wu.x), w1 = bfhi(wu.x), w2 = bflo(wu.y), w3 = bfhi(wu.y);
      acc1 += a1.x*w0 + a1.y*w1 + a1.z*w2 + a1.w*w3;
      acc2 += a2.x*w0 + a2.y*w1 + a2.z*w2 + a2.w*w3;
    }
    u16* o = H4 + (size_t)r*512 + g*256;
    o[d]      = f2bf(acc1);   // g0: h1   g1: ht1
    o[DD + d] = f2bf(acc2);   // g0: h2   g1: ht2
  }
}

// K2: bucket edges by destination row.
__global__ __launch_bounds__(256) void k2_bucket(
    const int* __restrict__ row, int E, int* __restrict__ deg,
    int* __restrict__ perm, int* __restrict__ ovfc, int* __restrict__ ovf)
{
  int e = blockIdx.x*256 + threadIdx.x;
  if (e >= E) return;
  int r = row[e];
  int slot = atomicAdd(&deg[r], 1);
  if (slot < CAP) perm[(size_t)r*CAP + slot] = e;
  else { int oi = atomicAdd(ovfc, 1); if (oi < 4096) ovf[oi] = e; }
}

// K3: one wave per row: AGG4[row] = sum_e val[e]*H4[col[e]] + bias  (fp32)
__global__ __launch_bounds__(256) void k3_spmm(
    const int* __restrict__ colI, const float* __restrict__ val,
    const int* __restrict__ deg, const int* __restrict__ perm,
    const u16* __restrict__ H4, const float* __restrict__ b, const float* __restrict__ bt,
    float* __restrict__ AGG4, int N)
{
  int row = blockIdx.x*4 + (threadIdx.x >> 6);
  int lane = threadIdx.x & 63;
  if (row >= N) return;
  int dg = deg[row]; if (dg > CAP) dg = CAP;
  float acc[8] = {0.f,0.f,0.f,0.f,0.f,0.f,0.f,0.f};
  const int boff = lane*8;     // element offset within the 512-wide row (16B/lane)
  for (int base = 0; base < dg; base += 64) {
    int e = -1;
    if (base + lane < dg) e = perm[(size_t)row*CAP + base + lane];
    int c = 0; float v = 0.f;
    if (e >= 0) { c = colI[e]; v = val[e]; }
    int m = dg - base; if (m > 64) m = 64;
    for (int j = 0; j < m; ++j) {
      int   cj = __shfl(c, j);
      float vj = __shfl(v, j);
      uint4 hv = *(const uint4*)(H4 + (size_t)cj*512 + boff);
      acc[0] += vj*bflo(hv.x); acc[1] += vj*bfhi(hv.x);
      acc[2] += vj*bflo(hv.y); acc[3] += vj*bfhi(hv.y);
      acc[4] += vj*bflo(hv.z); acc[5] += vj*bfhi(hv.z);
      acc[6] += vj*bflo(hv.w); acc[7] += vj*bfhi(hv.w);
    }
  }
  // bias: segments 0,1 (h1,h2) get b; segments 2,3 (ht1,ht2) get bt
  const float* __restrict__ bp = (lane < 32) ? b : bt;
  int d0 = (lane & 15) * 8;
  float* out = AGG4 + (size_t)row*512 + boff;
  float4 o0, o1;
  o0.x = acc[0] + bp[d0+0]; o0.y = acc[1] + bp[d0+1];
  o0.z = acc[2] + bp[d0+2]; o0.w = acc[3] + bp[d0+3];
  o1.x = acc[4] + bp[d0+4]; o1.y = acc[5] + bp[d0+5];
  o1.z = acc[6] + bp[d0+6]; o1.w = acc[7] + bp[d0+7];
  ((float4*)out)[0] = o0;
  ((float4*)out)[1] = o1;
}

// K3b: overflow edges (expected none) — atomic fallback.
__global__ __launch_bounds__(256) void k3b_ovf(
    const int* __restrict__ rowI, const int* __restrict__ colI,
    const float* __restrict__ val, const int* __restrict__ ovfc,
    const int* __restrict__ ovf, const u16* __restrict__ H4,
    float* __restrict__ AGG4)
{
  int n = *ovfc; if (n > 4096) n = 4096;
  for (int i = 0; i < n; ++i) {
    int e = ovf[i];
    int r = rowI[e], c = colI[e];
    float v = val[e];
    for (int dd2 = threadIdx.x; dd2 < 512; dd2 += 256)
      atomicAdd(&AGG4[(size_t)r*512 + dd2], v * bf2f(H4[(size_t)c*512 + dd2]));
  }
}

// K4: embed = (x + perb) + (agg2 + b)   (bias already folded into AGG4 seg1)
__global__ __launch_bounds__(256) void k4_embed(
    const float* __restrict__ x, const float* __restrict__ perb,
    const float* __restrict__ AGG4, float* __restrict__ out, int total)
{
  int idx = blockIdx.x*256 + threadIdx.x;
  if (idx >= total) return;
  int r = idx >> 7, d = idx & 127;
  out[idx] = x[idx] + perb[idx] + AGG4[(size_t)r*512 + 128 + d];
}

// K5: P = online @ W1 + b1 for px (half 0, AGG seg0) and py (half 1, AGG seg1),
//     fused per-column BN partial sums.
__global__ __launch_bounds__(256) void k5_pred1(
    const float* __restrict__ AGG4, const float* __restrict__ W1, const float* __restrict__ b1,
    float* __restrict__ Px, float* __restrict__ Py, float* __restrict__ stats, int N)
{
  __shared__ __align__(16) u16 WTl[DD*WT_STRIDE];   // 33792 B
  __shared__ __align__(16) float xs[2][16][DD];     // 16384 B
  const int tid = threadIdx.x;
  for (int i = tid; i < DD*DD; i += 256) {
    int k = i >> 7, d2 = i & 127;
    WTl[d2*WT_STRIDE + k] = f2bf(W1[i]);
  }
  const int r0 = blockIdx.x * 16;
  for (int idx = tid; idx < 16*256; idx += 256) {
    int rr = idx >> 8, j = idx & 255;
    int r = r0 + rr;
    float v = (r < N) ? AGG4[(size_t)r*512 + j] : 0.f;
    xs[j>>7][rr][j&127] = v;
  }
  __syncthreads();
  const int d = tid & 127, half = tid >> 7;
  const float bb = b1[d];
  float lsum = 0.f, lsq = 0.f;
  float* __restrict__ P = half ? Py : Px;
  for (int rr = 0; rr < 16; ++rr) {
    int r = r0 + rr;
    if (r >= N) break;   // uniform
    float acc = bb;
    #pragma unroll
    for (int k = 0; k < DD; k += 4) {
      float4 a = *(const float4*)&xs[half][rr][k];
      uint2 wu = *(const uint2*)&WTl[d*WT_STRIDE + k];
      acc += a.x*bflo(wu.x) + a.y*bfhi(wu.x) + a.z*bflo(wu.y) + a.w*bfhi(wu.y);
    }
    P[(size_t)r*DD + d] = acc;
    lsum += acc; lsq += acc*acc;
  }
  atomicAdd(&stats[half*256 + d], lsum);
  atomicAdd(&stats[half*256 + 128 + d], lsq);
}

// K6: BN + PReLU + GEMM2 + per-row BYOL cosine, loss accumulated into gloss.
__global__ __launch_bounds__(256) void k6_pred2_loss(
    const float* __restrict__ Px, const float* __restrict__ Py,
    const float* __restrict__ AGG4, const float* __restrict__ stats,
    const float* __restrict__ gamma, const float* __restrict__ beta,
    const float* __restrict__ aP, const float* __restrict__ W2, const float* __restrict__ b2,
    float* __restrict__ gloss, int N)
{
  __shared__ __align__(16) u16 WTl[DD*WT_STRIDE];
  __shared__ __align__(16) float hpl[2][DD];
  __shared__ float redl[4][3];
  const int tid = threadIdx.x;
  for (int i = tid; i < DD*DD; i += 256) {
    int k = i >> 7, d2 = i & 127;
    WTl[d2*WT_STRIDE + k] = f2bf(W2[i]);
  }
  const int d = tid & 127, half = tid >> 7;
  const int lane = tid & 63, wv = tid >> 6;
  const float invN = 1.f / (float)N;
  float mu  = stats[half*256 + d] * invN;
  float var = stats[half*256 + 128 + d] * invN - mu*mu;
  float rstd = rsqrtf(var + 1e-5f);
  float ga = gamma[d], be = beta[d];
  float alpha = aP[0];
  float bb = b2[d];
  const float* __restrict__ P = half ? Py : Px;
  const int toff = half ? 256 : 384;  // half0: target_x = seg3; half1: target_y = seg2
  const int r0 = blockIdx.x * 32;
  float lsum = 0.f;
  __syncthreads();
  for (int rr = 0; rr < 32; ++rr) {
    int r = r0 + rr;
    if (r >= N) break;   // uniform across block
    float v = P[(size_t)r*DD + d];
    float hn = (v - mu) * rstd * ga + be;
    float hp = hn >= 0.f ? hn : alpha * hn;
    hpl[half][d] = hp;
    __syncthreads();
    float px = bb;
    #pragma unroll
    for (int k = 0; k < DD; k += 4) {
      float4 a = *(const float4*)&hpl[half][k];
      uint2 wu = *(const uint2*)&WTl[d*WT_STRIDE + k];
      px += a.x*bflo(wu.x) + a.y*bfhi(wu.x) + a.z*bflo(wu.y) + a.w*bfhi(wu.y);
    }
    float t = AGG4[(size_t)r*512 + toff + d];
    float pp = px*px, tt = t*t, pt = px*t;
    #pragma unroll
    for (int off = 32; off > 0; off >>= 1) {
      pp += __shfl_xor(pp, off);
      tt += __shfl_xor(tt, off);
      pt += __shfl_xor(pt, off);
    }
    if (lane == 0) { redl[wv][0] = pp; redl[wv][1] = tt; redl[wv][2] = pt; }
    __syncthreads();
    if (tid == half*128) {
      int w0 = half*2;
      float ppS = redl[w0][0] + redl[w0+1][0];
      float ttS = redl[w0][1] + redl[w0+1][1];
      float ptS = redl[w0][2] + redl[w0+1][2];
      lsum += 2.f - 2.f * (ptS / sqrtf(ppS * ttS));
    }
    __syncthreads();
  }
  if (tid == 0 || tid == 128) atomicAdd(gloss, lsum);
}

__global__ void k7_loss(const float* __restrict__ gloss, float* __restrict__ out, int N, int total)
{
  out[total] = gloss[0] / (float)N;
}

extern "C" void kernel_launch(void* const* d_in, const int* in_sizes, int n_in,
                              void* d_out, int out_size, void* d_ws, size_t ws_size,
                              hipStream_t stream)
{
  const float* x    = (const float*)d_in[0];
  const float* perb = (const float*)d_in[1];
  const int*   erow = (const int*)d_in[2];
  const int*   ecol = (const int*)d_in[3];
  const float* eval_= (const float*)d_in[4];
  const float* W    = (const float*)d_in[5];
  const float* b    = (const float*)d_in[6];
  const float* Wt   = (const float*)d_in[7];
  const float* bt   = (const float*)d_in[8];
  const float* W1   = (const float*)d_in[9];
  const float* b1   = (const float*)d_in[10];
  const float* gam  = (const float*)d_in[11];
  const float* bet  = (const float*)d_in[12];
  const float* aP   = (const float*)d_in[13];
  const float* W2   = (const float*)d_in[14];
  const float* b2   = (const float*)d_in[15];
  const int N = in_sizes[0] / DD;
  const int E = in_sizes[2];

  char* ws = (char*)d_ws;
  size_t off = 0;
  auto alloc = [&](size_t bytes) -> void* {
    void* p = ws + off;
    off += (bytes + 255) & ~(size_t)255;
    return p;
  };
  float* AGG4 = (float*)alloc((size_t)N*512*sizeof(float)); // 102.4 MB
  u16*   H4   = (u16*)  alloc((size_t)N*512*sizeof(u16));   // 51.2 MB (reused as Px/Py)
  size_t zoff = off;                                        // ---- zeroed region ----
  int*   deg  = (int*)  alloc((size_t)N*sizeof(int));
  float* stats= (float*)alloc(512*sizeof(float));
  float* gloss= (float*)alloc(256);
  int*   ovfc = (int*)((char*)gloss + 64);
  size_t zbytes = off - zoff;                               // ---- end zeroed ----
  int*   perm = (int*)  alloc((size_t)N*CAP*sizeof(int));   // 19.2 MB
  int*   ovf  = (int*)  alloc(4096*sizeof(int));
  if (ws_size < off) return;   // visible failure if workspace too small

  float* Px = (float*)H4;            // H4 dead after k3b; 51.2MB == 2*25.6MB exactly
  float* Py = Px + (size_t)N*DD;

  hipMemsetAsync(ws + zoff, 0, zbytes, stream);
  dim3 g1((N + 15)/16, 2);
  k1_gemm_h4<<<g1, 256, 0, stream>>>(x, perb, W, Wt, H4, N);
  k2_bucket<<<(E + 255)/256, 256, 0, stream>>>(erow, E, deg, perm, ovfc, ovf);
  k3_spmm<<<(N + 3)/4, 256, 0, stream>>>(ecol, eval_, deg, perm, H4, b, bt, AGG4, N);
  k3b_ovf<<<1, 256, 0, stream>>>(erow, ecol, eval_, ovfc, ovf, H4, AGG4);
  k4_embed<<<(N*DD + 255)/256, 256, 0, stream>>>(x, perb, AGG4, (float*)d_out, N*DD);
  k5_pred1<<<(N + 15)/16, 256, 0, stream>>>(AGG4, W1, b1, Px, Py, stats, N);
  k6_pred2_loss<<<(N + 31)/32, 256, 0, stream>>>(Px, Py, AGG4, stats, gam, bet, aP, W2, b2, gloss, N);
  k7_loss<<<1, 1, 0, stream>>>(gloss, (float*)d_out, N, N*DD);
}

// Round 3
// 706.775 us; speedup vs baseline: 1.2922x; 1.2922x over previous
//
#include <hip/hip_runtime.h>
#include <stdint.h>

typedef unsigned short u16;
typedef unsigned int u32;
typedef __attribute__((ext_vector_type(8))) short bf16x8;
typedef __attribute__((ext_vector_type(4))) short bf16x4;
typedef __attribute__((ext_vector_type(4))) float f32x4;

#define DD 128
#define CAP 96
#define STRA 136   // A-tile LDS stride (u16): 272B rows, 16B-aligned, 2-way max conflict
#define STRC1 264  // k1 C-tile stride (u16): 528B rows, 16B-aligned
#define STRCF 132  // k5/k6 C-tile stride (f32): 528B rows, 16B-aligned

__device__ __forceinline__ float bflo(u32 u){ return __uint_as_float(u<<16); }
__device__ __forceinline__ float bfhi(u32 u){ return __uint_as_float(u & 0xffff0000u); }
__device__ __forceinline__ float bf2f(u16 u){ return __uint_as_float(((u32)u)<<16); }
__device__ __forceinline__ u16 f2bf(float f){
  u32 u = __float_as_uint(f);
  return (u16)((u + 0x7fffu + ((u>>16)&1u)) >> 16);   // RNE
}

// K0: pre-swizzle weights into MFMA B-fragment order.
// Bswz idx = ((kt*16+nt)*64 + lane)*8 + j  <- B'[kt*32+(lane>>4)*8+j][nt*16+(lane&15)], B'=[W|Wt]
// W1swz/W2swz same with 8 n-tiles.
__global__ __launch_bounds__(256) void k0_swz(
    const float* __restrict__ W, const float* __restrict__ Wt,
    const float* __restrict__ W1, const float* __restrict__ W2,
    u16* __restrict__ Bswz, u16* __restrict__ W1swz, u16* __restrict__ W2swz)
{
  int idx = blockIdx.x*256 + threadIdx.x;
  if (idx < 32768) {
    int j = idx & 7, lane = (idx>>3)&63, nt = (idx>>9)&15, kt = idx>>13;
    int k = kt*32 + (lane>>4)*8 + j, n = nt*16 + (lane&15);
    float v = (n < DD) ? W[k*DD + n] : Wt[k*DD + (n-DD)];
    Bswz[idx] = f2bf(v);
  } else {
    int t = idx - 32768;
    int which = t >> 14; t &= 16383;
    int j = t & 7, lane = (t>>3)&63, nt = (t>>9)&7, kt = (t>>12)&3;
    int k = kt*32 + (lane>>4)*8 + j, n = nt*16 + (lane&15);
    const float* __restrict__ src = which ? W2 : W1;
    u16* __restrict__ dst = which ? W2swz : W1swz;
    dst[t] = f2bf(src[k*DD + n]);
  }
}

// K1: MFMA GEMM. A-rows 0-31 = bf16(x[r0..]), 32-63 = bf16(x+perb). B = [W|Wt] (256 cols).
// Output row remap: H2[2r] = [h1|ht1](r), H2[2r+1] = [h2|ht2](r) — 1KB-contiguous per source col.
__global__ __launch_bounds__(256) void k1_gemm(
    const float* __restrict__ x, const float* __restrict__ perb,
    const u16* __restrict__ Bswz, u16* __restrict__ H2, int N)
{
  __shared__ __align__(16) u16 As[64*STRA];
  __shared__ __align__(16) u16 Cs[64*STRC1];
  const int tid = threadIdx.x;
  const int r0 = blockIdx.x * 32;
  #pragma unroll
  for (int i = 0; i < 4; ++i) {
    int f = tid + 256*i;            // 1024 float4 slots: 32 rows x 32
    int row = f >> 5, c4 = f & 31;
    int r = r0 + row;
    float4 xv = make_float4(0.f,0.f,0.f,0.f), pv = xv;
    if (r < N) {
      xv = *(const float4*)&x[(size_t)r*DD + c4*4];
      pv = *(const float4*)&perb[(size_t)r*DD + c4*4];
    }
    bf16x4 a, s;
    a.x = (short)f2bf(xv.x); a.y = (short)f2bf(xv.y);
    a.z = (short)f2bf(xv.z); a.w = (short)f2bf(xv.w);
    s.x = (short)f2bf(xv.x+pv.x); s.y = (short)f2bf(xv.y+pv.y);
    s.z = (short)f2bf(xv.z+pv.z); s.w = (short)f2bf(xv.w+pv.w);
    *(bf16x4*)&As[row*STRA + c4*4]      = a;
    *(bf16x4*)&As[(32+row)*STRA + c4*4] = s;
  }
  __syncthreads();
  const int w = tid >> 6, l = tid & 63;
  const int m = l & 15, q = l >> 4;
  f32x4 acc[16];
  #pragma unroll
  for (int nt = 0; nt < 16; ++nt) acc[nt] = (f32x4){0.f,0.f,0.f,0.f};
  const int arow = w*16 + m;
  #pragma unroll
  for (int kt = 0; kt < 4; ++kt) {
    bf16x8 af = *(const bf16x8*)&As[arow*STRA + kt*32 + q*8];
    #pragma unroll
    for (int nt = 0; nt < 16; ++nt) {
      bf16x8 bf = *(const bf16x8*)(Bswz + ((size_t)(kt*16+nt)*64 + l)*8);
      acc[nt] = __builtin_amdgcn_mfma_f32_16x16x32_bf16(af, bf, acc[nt], 0, 0, 0);
    }
  }
  // stage C (bf16) — C layout: col=l&15, row=q*4+reg
  #pragma unroll
  for (int nt = 0; nt < 16; ++nt)
    #pragma unroll
    for (int i = 0; i < 4; ++i)
      Cs[(w*16 + q*4 + i)*STRC1 + nt*16 + m] = f2bf(acc[nt][i]);
  __syncthreads();
  const int ar = tid >> 2, p = tid & 3;   // 64 rows x 4 pieces of 128B
  const int src = r0 + (ar & 31);
  if (src < N) {
    size_t grow = (size_t)src*2 + (ar >> 5);
    const u16* sp = &Cs[ar*STRC1 + p*64];
    u16* dp = H2 + grow*256 + p*64;
    #pragma unroll
    for (int i = 0; i < 8; ++i)
      *(bf16x8*)(dp + i*8) = *(const bf16x8*)(sp + i*8);
  }
}

// K2: bucket edges by destination row.
__global__ __launch_bounds__(256) void k2_bucket(
    const int* __restrict__ row, int E, int* __restrict__ deg,
    int* __restrict__ perm, int* __restrict__ ovfc, int* __restrict__ ovf)
{
  int e = blockIdx.x*256 + threadIdx.x;
  if (e >= E) return;
  int r = row[e];
  int slot = atomicAdd(&deg[r], 1);
  if (slot < CAP) perm[(size_t)r*CAP + slot] = e;
  else { int oi = atomicAdd(ovfc, 1); if (oi < 4096) ovf[oi] = e; }
}

// K3: one wave per row. H2 pair rows (2c,2c+1) are the contiguous 512-elem block at c*512.
// Segments: lanes 0-15: h1(+b) -> s0 | 16-31: ht1(+bt) -> s1 | 32-47: h2(+b) -> s2 | 48-63: ht2(+bt) -> s3
__global__ __launch_bounds__(256) void k3_spmm(
    const int* __restrict__ colI, const float* __restrict__ val,
    const int* __restrict__ deg, const int* __restrict__ perm,
    const u16* __restrict__ H2, const float* __restrict__ b, const float* __restrict__ bt,
    float* __restrict__ AGG4, int N)
{
  int row = blockIdx.x*4 + (threadIdx.x >> 6);
  int lane = threadIdx.x & 63;
  if (row >= N) return;
  int dg = deg[row]; if (dg > CAP) dg = CAP;
  float acc[8] = {0.f,0.f,0.f,0.f,0.f,0.f,0.f,0.f};
  const int boff = lane*8;
  for (int base = 0; base < dg; base += 64) {
    int e = -1;
    if (base + lane < dg) e = perm[(size_t)row*CAP + base + lane];
    int c = 0; float v = 0.f;
    if (e >= 0) { c = colI[e]; v = val[e]; }
    int mm = dg - base; if (mm > 64) mm = 64;
    for (int j = 0; j < mm; ++j) {
      int   cj = __shfl(c, j);
      float vj = __shfl(v, j);
      uint4 hv = *(const uint4*)(H2 + (size_t)cj*512 + boff);
      acc[0] += vj*bflo(hv.x); acc[1] += vj*bfhi(hv.x);
      acc[2] += vj*bflo(hv.y); acc[3] += vj*bfhi(hv.y);
      acc[4] += vj*bflo(hv.z); acc[5] += vj*bfhi(hv.z);
      acc[6] += vj*bflo(hv.w); acc[7] += vj*bfhi(hv.w);
    }
  }
  const float* __restrict__ bp = (((lane>>4)&1)==0) ? b : bt;
  int d0 = (lane & 15) * 8;
  float* out = AGG4 + (size_t)row*512 + boff;
  float4 o0, o1;
  o0.x = acc[0] + bp[d0+0]; o0.y = acc[1] + bp[d0+1];
  o0.z = acc[2] + bp[d0+2]; o0.w = acc[3] + bp[d0+3];
  o1.x = acc[4] + bp[d0+4]; o1.y = acc[5] + bp[d0+5];
  o1.z = acc[6] + bp[d0+6]; o1.w = acc[7] + bp[d0+7];
  ((float4*)out)[0] = o0;
  ((float4*)out)[1] = o1;
}

// K3b: overflow fallback (expected empty).
__global__ __launch_bounds__(256) void k3b_ovf(
    const int* __restrict__ rowI, const int* __restrict__ colI,
    const float* __restrict__ val, const int* __restrict__ ovfc,
    const int* __restrict__ ovf, const u16* __restrict__ H2,
    float* __restrict__ AGG4)
{
  int n = *ovfc; if (n > 4096) n = 4096;
  for (int i = 0; i < n; ++i) {
    int e = ovf[i];
    int r = rowI[e], c = colI[e];
    float v = val[e];
    for (int dd2 = threadIdx.x; dd2 < 512; dd2 += 256)
      atomicAdd(&AGG4[(size_t)r*512 + dd2], v * bf2f(H2[(size_t)c*512 + dd2]));
  }
}

// K4: embed = (x + perb) + s2    (s2 = agg(h2)+b at offset 256)
__global__ __launch_bounds__(256) void k4_embed(
    const float* __restrict__ x, const float* __restrict__ perb,
    const float* __restrict__ AGG4, float* __restrict__ out, int n4)
{
  int idx = blockIdx.x*256 + threadIdx.x;
  if (idx >= n4) return;
  int r = idx >> 5, c4 = idx & 31;
  float4 xv = *(const float4*)&x[(size_t)r*DD + c4*4];
  float4 pv = *(const float4*)&perb[(size_t)r*DD + c4*4];
  float4 av = *(const float4*)&AGG4[(size_t)r*512 + 256 + c4*4];
  float4 o; o.x = xv.x+pv.x+av.x; o.y = xv.y+pv.y+av.y;
  o.z = xv.z+pv.z+av.z; o.w = xv.w+pv.w+av.w;
  *(float4*)&out[(size_t)r*DD + c4*4] = o;
}

// K5: P = AGG_seg @ W1 + b1 (MFMA), fused BN column sums. y=0: s0->Px, y=1: s2->Py.
__global__ __launch_bounds__(256) void k5_gemm(
    const float* __restrict__ AGG4, const u16* __restrict__ W1swz,
    const float* __restrict__ b1, float* __restrict__ Px, float* __restrict__ Py,
    float* __restrict__ stats, int N)
{
  __shared__ __align__(16) u16 As[64*STRA];
  __shared__ __align__(16) float Cs[64*STRCF];
  const int tid = threadIdx.x;
  const int seg = blockIdx.y;
  const int soff = seg ? 256 : 0;
  const int r0 = blockIdx.x * 64;
  #pragma unroll
  for (int i = 0; i < 8; ++i) {
    int f = tid + 256*i;            // 2048 float4: 64 rows x 32
    int row = f >> 5, c4 = f & 31;
    int r = r0 + row;
    float4 v = make_float4(0.f,0.f,0.f,0.f);
    if (r < N) v = *(const float4*)&AGG4[(size_t)r*512 + soff + c4*4];
    bf16x4 a;
    a.x = (short)f2bf(v.x); a.y = (short)f2bf(v.y);
    a.z = (short)f2bf(v.z); a.w = (short)f2bf(v.w);
    *(bf16x4*)&As[row*STRA + c4*4] = a;
  }
  __syncthreads();
  const int w = tid >> 6, l = tid & 63;
  const int m = l & 15, q = l >> 4;
  f32x4 acc[8];
  #pragma unroll
  for (int nt = 0; nt < 8; ++nt) acc[nt] = (f32x4){0.f,0.f,0.f,0.f};
  const int arow = w*16 + m;
  #pragma unroll
  for (int kt = 0; kt < 4; ++kt) {
    bf16x8 af = *(const bf16x8*)&As[arow*STRA + kt*32 + q*8];
    #pragma unroll
    for (int nt = 0; nt < 8; ++nt) {
      bf16x8 bf = *(const bf16x8*)(W1swz + ((size_t)(kt*8+nt)*64 + l)*8);
      acc[nt] = __builtin_amdgcn_mfma_f32_16x16x32_bf16(af, bf, acc[nt], 0, 0, 0);
    }
  }
  // bias (valid rows only) + column stats
  const int rbase = r0 + w*16 + q*4;
  #pragma unroll
  for (int nt = 0; nt < 8; ++nt) {
    float bv = b1[nt*16 + m];
    float sum = 0.f, sq = 0.f;
    #pragma unroll
    for (int i = 0; i < 4; ++i) {
      if (rbase + i < N) acc[nt][i] += bv; else acc[nt][i] = 0.f;
      sum += acc[nt][i]; sq += acc[nt][i]*acc[nt][i];
    }
    sum += __shfl_xor(sum, 16); sum += __shfl_xor(sum, 32);
    sq  += __shfl_xor(sq, 16);  sq  += __shfl_xor(sq, 32);
    if (l < 16) {
      atomicAdd(&stats[seg*256 + nt*16 + l], sum);
      atomicAdd(&stats[seg*256 + 128 + nt*16 + l], sq);
    }
  }
  #pragma unroll
  for (int nt = 0; nt < 8; ++nt)
    #pragma unroll
    for (int i = 0; i < 4; ++i)
      Cs[(w*16 + q*4 + i)*STRCF + nt*16 + m] = acc[nt][i];
  __syncthreads();
  const int ar = tid >> 2, p = tid & 3;
  const int r = r0 + ar;
  float* __restrict__ P = seg ? Py : Px;
  if (r < N) {
    const float* sp = &Cs[ar*STRCF + p*32];
    float* dp = &P[(size_t)r*DD + p*32];
    #pragma unroll
    for (int i = 0; i < 8; ++i)
      *(float4*)(dp + i*4) = *(const float4*)(sp + i*4);
  }
}

// K6: BN+PReLU prologue -> MFMA GEMM2 (+b2) -> per-row BYOL cosine vs target -> gloss.
// y=0: Px vs s3 (toff 384); y=1: Py vs s1 (toff 128).
__global__ __launch_bounds__(256) void k6_gemm_loss(
    const float* __restrict__ Px, const float* __restrict__ Py,
    const float* __restrict__ AGG4, const float* __restrict__ stats,
    const float* __restrict__ gamma, const float* __restrict__ beta,
    const float* __restrict__ aP, const u16* __restrict__ W2swz,
    const float* __restrict__ b2, float* __restrict__ gloss, int N)
{
  __shared__ __align__(16) u16 As[64*STRA];
  __shared__ __align__(16) float Cs[64*STRCF];
  __shared__ float s1s[128], s2s[128];
  const int tid = threadIdx.x;
  const int seg = blockIdx.y;
  const float* __restrict__ P = seg ? Py : Px;
  const int toff = seg ? 128 : 384;
  const float invN = 1.f / (float)N;
  if (tid < 128) {
    float mu = stats[seg*256 + tid] * invN;
    float var = stats[seg*256 + 128 + tid] * invN - mu*mu;
    float rstd = rsqrtf(var + 1e-5f);
    float s1 = rstd * gamma[tid];
    s1s[tid] = s1;
    s2s[tid] = beta[tid] - mu*s1;
  }
  const float alpha = aP[0];
  const int r0 = blockIdx.x * 64;
  __syncthreads();
  #pragma unroll
  for (int i = 0; i < 8; ++i) {
    int f = tid + 256*i;
    int row = f >> 5, c4 = f & 31;
    int r = r0 + row;
    float4 v = make_float4(0.f,0.f,0.f,0.f);
    if (r < N) v = *(const float4*)&P[(size_t)r*DD + c4*4];
    float h0 = v.x*s1s[c4*4+0] + s2s[c4*4+0];
    float h1 = v.y*s1s[c4*4+1] + s2s[c4*4+1];
    float h2 = v.z*s1s[c4*4+2] + s2s[c4*4+2];
    float h3 = v.w*s1s[c4*4+3] + s2s[c4*4+3];
    h0 = h0 >= 0.f ? h0 : alpha*h0;  h1 = h1 >= 0.f ? h1 : alpha*h1;
    h2 = h2 >= 0.f ? h2 : alpha*h2;  h3 = h3 >= 0.f ? h3 : alpha*h3;
    bf16x4 a;
    a.x = (short)f2bf(h0); a.y = (short)f2bf(h1);
    a.z = (short)f2bf(h2); a.w = (short)f2bf(h3);
    *(bf16x4*)&As[row*STRA + c4*4] = a;
  }
  __syncthreads();
  const int w = tid >> 6, l = tid & 63;
  const int m = l & 15, q = l >> 4;
  f32x4 acc[8];
  #pragma unroll
  for (int nt = 0; nt < 8; ++nt) acc[nt] = (f32x4){0.f,0.f,0.f,0.f};
  const int arow = w*16 + m;
  #pragma unroll
  for (int kt = 0; kt < 4; ++kt) {
    bf16x8 af = *(const bf16x8*)&As[arow*STRA + kt*32 + q*8];
    #pragma unroll
    for (int nt = 0; nt < 8; ++nt) {
      bf16x8 bf = *(const bf16x8*)(W2swz + ((size_t)(kt*8+nt)*64 + l)*8);
      acc[nt] = __builtin_amdgcn_mfma_f32_16x16x32_bf16(af, bf, acc[nt], 0, 0, 0);
    }
  }
  #pragma unroll
  for (int nt = 0; nt < 8; ++nt) {
    float bv = b2[nt*16 + m];
    #pragma unroll
    for (int i = 0; i < 4; ++i)
      Cs[(w*16 + q*4 + i)*STRCF + nt*16 + m] = acc[nt][i] + bv;
  }
  __syncthreads();
  float lsum = 0.f;
  for (int rr = 0; rr < 16; ++rr) {
    int ar = w*16 + rr;
    int r = r0 + ar;
    if (r >= N) break;   // uniform within wave
    float2 pv = *(const float2*)&Cs[ar*STRCF + l*2];
    float2 tv = *(const float2*)&AGG4[(size_t)r*512 + toff + l*2];
    float pp = pv.x*pv.x + pv.y*pv.y;
    float tt = tv.x*tv.x + tv.y*tv.y;
    float pt = pv.x*tv.x + pv.y*tv.y;
    #pragma unroll
    for (int off = 1; off <= 32; off <<= 1) {
      pp += __shfl_xor(pp, off);
      tt += __shfl_xor(tt, off);
      pt += __shfl_xor(pt, off);
    }
    if (l == 0) lsum += 2.f - 2.f * pt * rsqrtf(pp * tt);
  }
  if ((tid & 63) == 0) atomicAdd(gloss, lsum);
}

__global__ void k7_loss(const float* __restrict__ gloss, float* __restrict__ out, int N, int total)
{
  out[total] = gloss[0] / (float)N;
}

extern "C" void kernel_launch(void* const* d_in, const int* in_sizes, int n_in,
                              void* d_out, int out_size, void* d_ws, size_t ws_size,
                              hipStream_t stream)
{
  const float* x    = (const float*)d_in[0];
  const float* perb = (const float*)d_in[1];
  const int*   erow = (const int*)d_in[2];
  const int*   ecol = (const int*)d_in[3];
  const float* eval_= (const float*)d_in[4];
  const float* W    = (const float*)d_in[5];
  const float* b    = (const float*)d_in[6];
  const float* Wt   = (const float*)d_in[7];
  const float* bt   = (const float*)d_in[8];
  const float* W1   = (const float*)d_in[9];
  const float* b1   = (const float*)d_in[10];
  const float* gam  = (const float*)d_in[11];
  const float* bet  = (const float*)d_in[12];
  const float* aP   = (const float*)d_in[13];
  const float* W2   = (const float*)d_in[14];
  const float* b2   = (const float*)d_in[15];
  const int N = in_sizes[0] / DD;
  const int E = in_sizes[2];

  char* ws = (char*)d_ws;
  size_t off = 0;
  auto alloc = [&](size_t bytes) -> void* {
    void* p = ws + off;
    off += (bytes + 255) & ~(size_t)255;
    return p;
  };
  float* AGG4 = (float*)alloc((size_t)N*512*sizeof(float)); // 102.4 MB
  u16*   H2   = (u16*)  alloc((size_t)N*512*sizeof(u16));   // 51.2 MB (reused as Px/Py)
  size_t zoff = off;                                        // ---- zeroed region ----
  int*   deg  = (int*)  alloc((size_t)N*sizeof(int));
  float* stats= (float*)alloc(512*sizeof(float));
  float* gloss= (float*)alloc(256);
  int*   ovfc = (int*)((char*)gloss + 64);
  size_t zbytes = off - zoff;                               // ---- end zeroed ----
  int*   perm = (int*)  alloc((size_t)N*CAP*sizeof(int));   // 19.2 MB
  int*   ovf  = (int*)  alloc(4096*sizeof(int));
  u16*   Bswz = (u16*)  alloc(32768*sizeof(u16));
  u16*   W1swz= (u16*)  alloc(16384*sizeof(u16));
  u16*   W2swz= (u16*)  alloc(16384*sizeof(u16));
  if (ws_size < off) return;

  float* Px = (float*)H2;            // H2 dead after k3b
  float* Py = Px + (size_t)N*DD;

  hipMemsetAsync(ws + zoff, 0, zbytes, stream);
  k0_swz<<<256, 256, 0, stream>>>(W, Wt, W1, W2, Bswz, W1swz, W2swz);
  k1_gemm<<<(N + 31)/32, 256, 0, stream>>>(x, perb, Bswz, H2, N);
  k2_bucket<<<(E + 255)/256, 256, 0, stream>>>(erow, E, deg, perm, ovfc, ovf);
  k3_spmm<<<(N + 3)/4, 256, 0, stream>>>(ecol, eval_, deg, perm, H2, b, bt, AGG4, N);
  k3b_ovf<<<1, 256, 0, stream>>>(erow, ecol, eval_, ovfc, ovf, H2, AGG4);
  k4_embed<<<(N*32 + 255)/256, 256, 0, stream>>>(x, perb, AGG4, (float*)d_out, N*32);
  k5_gemm<<<dim3((N + 63)/64, 2), 256, 0, stream>>>(AGG4, W1swz, b1, Px, Py, stats, N);
  k6_gemm_loss<<<dim3((N + 63)/64, 2), 256, 0, stream>>>(Px, Py, AGG4, stats, gam, bet, aP, W2swz, b2, gloss, N);
  k7_loss<<<1, 1, 0, stream>>>(gloss, (float*)d_out, N, N*DD);
}

// Round 4
// 486.972 us; speedup vs baseline: 1.8754x; 1.4514x over previous
//
#include <hip/hip_runtime.h>
#include <stdint.h>

typedef unsigned short u16;
typedef unsigned int u32;
typedef __attribute__((ext_vector_type(8))) short bf16x8;
typedef __attribute__((ext_vector_type(4))) short bf16x4;
typedef __attribute__((ext_vector_type(4))) float f32x4;

#define DD 128
#define CAP 96
#define STRA 136   // A-tile LDS stride (u16): 272B rows, 16B-aligned
#define STRC1 264  // k1 C-tile stride (u16): 528B rows, 16B-aligned
#define STRCF 132  // k5/k6 C-tile stride (f32): 528B rows, 16B-aligned

__device__ __forceinline__ float bflo(u32 u){ return __uint_as_float(u<<16); }
__device__ __forceinline__ float bfhi(u32 u){ return __uint_as_float(u & 0xffff0000u); }
__device__ __forceinline__ float bf2f(u16 u){ return __uint_as_float(((u32)u)<<16); }
__device__ __forceinline__ u16 f2bf(float f){
  u32 u = __float_as_uint(f);
  return (u16)((u + 0x7fffu + ((u>>16)&1u)) >> 16);   // RNE
}

// K0: pre-swizzle weights into MFMA B-fragment order.
__global__ __launch_bounds__(256) void k0_swz(
    const float* __restrict__ W, const float* __restrict__ Wt,
    const float* __restrict__ W1, const float* __restrict__ W2,
    u16* __restrict__ Bswz, u16* __restrict__ W1swz, u16* __restrict__ W2swz)
{
  int idx = blockIdx.x*256 + threadIdx.x;
  if (idx < 32768) {
    int j = idx & 7, lane = (idx>>3)&63, nt = (idx>>9)&15, kt = idx>>13;
    int k = kt*32 + (lane>>4)*8 + j, n = nt*16 + (lane&15);
    float v = (n < DD) ? W[k*DD + n] : Wt[k*DD + (n-DD)];
    Bswz[idx] = f2bf(v);
  } else {
    int t = idx - 32768;
    int which = t >> 14; t &= 16383;
    int j = t & 7, lane = (t>>3)&63, nt = (t>>9)&7, kt = (t>>12)&3;
    int k = kt*32 + (lane>>4)*8 + j, n = nt*16 + (lane&15);
    const float* __restrict__ src = which ? W2 : W1;
    u16* __restrict__ dst = which ? W2swz : W1swz;
    dst[t] = f2bf(src[k*DD + n]);
  }
}

// K1: MFMA GEMM. A-rows 0-31 = bf16(x), 32-63 = bf16(x+perb). B = [W|Wt].
// H2[2r] = [h1|ht1](r), H2[2r+1] = [h2|ht2](r).
__global__ __launch_bounds__(256) void k1_gemm(
    const float* __restrict__ x, const float* __restrict__ perb,
    const u16* __restrict__ Bswz, u16* __restrict__ H2, int N)
{
  __shared__ __align__(16) u16 As[64*STRA];
  __shared__ __align__(16) u16 Cs[64*STRC1];
  const int tid = threadIdx.x;
  const int r0 = blockIdx.x * 32;
  #pragma unroll
  for (int i = 0; i < 4; ++i) {
    int f = tid + 256*i;
    int row = f >> 5, c4 = f & 31;
    int r = r0 + row;
    float4 xv = make_float4(0.f,0.f,0.f,0.f), pv = xv;
    if (r < N) {
      xv = *(const float4*)&x[(size_t)r*DD + c4*4];
      pv = *(const float4*)&perb[(size_t)r*DD + c4*4];
    }
    bf16x4 a, s;
    a.x = (short)f2bf(xv.x); a.y = (short)f2bf(xv.y);
    a.z = (short)f2bf(xv.z); a.w = (short)f2bf(xv.w);
    s.x = (short)f2bf(xv.x+pv.x); s.y = (short)f2bf(xv.y+pv.y);
    s.z = (short)f2bf(xv.z+pv.z); s.w = (short)f2bf(xv.w+pv.w);
    *(bf16x4*)&As[row*STRA + c4*4]      = a;
    *(bf16x4*)&As[(32+row)*STRA + c4*4] = s;
  }
  __syncthreads();
  const int w = tid >> 6, l = tid & 63;
  const int m = l & 15, q = l >> 4;
  f32x4 acc[16];
  #pragma unroll
  for (int nt = 0; nt < 16; ++nt) acc[nt] = (f32x4){0.f,0.f,0.f,0.f};
  const int arow = w*16 + m;
  #pragma unroll
  for (int kt = 0; kt < 4; ++kt) {
    bf16x8 af = *(const bf16x8*)&As[arow*STRA + kt*32 + q*8];
    #pragma unroll
    for (int nt = 0; nt < 16; ++nt) {
      bf16x8 bf = *(const bf16x8*)(Bswz + ((size_t)(kt*16+nt)*64 + l)*8);
      acc[nt] = __builtin_amdgcn_mfma_f32_16x16x32_bf16(af, bf, acc[nt], 0, 0, 0);
    }
  }
  #pragma unroll
  for (int nt = 0; nt < 16; ++nt)
    #pragma unroll
    for (int i = 0; i < 4; ++i)
      Cs[(w*16 + q*4 + i)*STRC1 + nt*16 + m] = f2bf(acc[nt][i]);
  __syncthreads();
  const int ar = tid >> 2, p = tid & 3;
  const int src = r0 + (ar & 31);
  if (src < N) {
    size_t grow = (size_t)src*2 + (ar >> 5);
    const u16* sp = &Cs[ar*STRC1 + p*64];
    u16* dp = H2 + grow*256 + p*64;
    #pragma unroll
    for (int i = 0; i < 8; ++i)
      *(bf16x8*)(dp + i*8) = *(const bf16x8*)(sp + i*8);
  }
}

// K2: bucket edges by destination row.
__global__ __launch_bounds__(256) void k2_bucket(
    const int* __restrict__ row, int E, int* __restrict__ deg,
    int* __restrict__ perm, int* __restrict__ ovfc, int* __restrict__ ovf)
{
  int e = blockIdx.x*256 + threadIdx.x;
  if (e >= E) return;
  int r = row[e];
  int slot = atomicAdd(&deg[r], 1);
  if (slot < CAP) perm[(size_t)r*CAP + slot] = e;
  else { int oi = atomicAdd(ovfc, 1); if (oi < 4096) ovf[oi] = e; }
}

// K3: one wave per row gather-accumulate over H2, bias fused.
__global__ __launch_bounds__(256) void k3_spmm(
    const int* __restrict__ colI, const float* __restrict__ val,
    const int* __restrict__ deg, const int* __restrict__ perm,
    const u16* __restrict__ H2, const float* __restrict__ b, const float* __restrict__ bt,
    float* __restrict__ AGG4, int N)
{
  int row = blockIdx.x*4 + (threadIdx.x >> 6);
  int lane = threadIdx.x & 63;
  if (row >= N) return;
  int dg = deg[row]; if (dg > CAP) dg = CAP;
  float acc[8] = {0.f,0.f,0.f,0.f,0.f,0.f,0.f,0.f};
  const int boff = lane*8;
  for (int base = 0; base < dg; base += 64) {
    int e = -1;
    if (base + lane < dg) e = perm[(size_t)row*CAP + base + lane];
    int c = 0; float v = 0.f;
    if (e >= 0) { c = colI[e]; v = val[e]; }
    int mm = dg - base; if (mm > 64) mm = 64;
    for (int j = 0; j < mm; ++j) {
      int   cj = __shfl(c, j);
      float vj = __shfl(v, j);
      uint4 hv = *(const uint4*)(H2 + (size_t)cj*512 + boff);
      acc[0] += vj*bflo(hv.x); acc[1] += vj*bfhi(hv.x);
      acc[2] += vj*bflo(hv.y); acc[3] += vj*bfhi(hv.y);
      acc[4] += vj*bflo(hv.z); acc[5] += vj*bfhi(hv.z);
      acc[6] += vj*bflo(hv.w); acc[7] += vj*bfhi(hv.w);
    }
  }
  const float* __restrict__ bp = (((lane>>4)&1)==0) ? b : bt;
  int d0 = (lane & 15) * 8;
  float* out = AGG4 + (size_t)row*512 + boff;
  float4 o0, o1;
  o0.x = acc[0] + bp[d0+0]; o0.y = acc[1] + bp[d0+1];
  o0.z = acc[2] + bp[d0+2]; o0.w = acc[3] + bp[d0+3];
  o1.x = acc[4] + bp[d0+4]; o1.y = acc[5] + bp[d0+5];
  o1.z = acc[6] + bp[d0+6]; o1.w = acc[7] + bp[d0+7];
  ((float4*)out)[0] = o0;
  ((float4*)out)[1] = o1;
}

// K3b: overflow fallback (expected empty).
__global__ __launch_bounds__(256) void k3b_ovf(
    const int* __restrict__ rowI, const int* __restrict__ colI,
    const float* __restrict__ val, const int* __restrict__ ovfc,
    const int* __restrict__ ovf, const u16* __restrict__ H2,
    float* __restrict__ AGG4)
{
  int n = *ovfc; if (n > 4096) n = 4096;
  for (int i = 0; i < n; ++i) {
    int e = ovf[i];
    int r = rowI[e], c = colI[e];
    float v = val[e];
    for (int dd2 = threadIdx.x; dd2 < 512; dd2 += 256)
      atomicAdd(&AGG4[(size_t)r*512 + dd2], v * bf2f(H2[(size_t)c*512 + dd2]));
  }
}

// K4: embed = (x + perb) + s2
__global__ __launch_bounds__(256) void k4_embed(
    const float* __restrict__ x, const float* __restrict__ perb,
    const float* __restrict__ AGG4, float* __restrict__ out, int n4)
{
  int idx = blockIdx.x*256 + threadIdx.x;
  if (idx >= n4) return;
  int r = idx >> 5, c4 = idx & 31;
  float4 xv = *(const float4*)&x[(size_t)r*DD + c4*4];
  float4 pv = *(const float4*)&perb[(size_t)r*DD + c4*4];
  float4 av = *(const float4*)&AGG4[(size_t)r*512 + 256 + c4*4];
  float4 o; o.x = xv.x+pv.x+av.x; o.y = xv.y+pv.y+av.y;
  o.z = xv.z+pv.z+av.z; o.w = xv.w+pv.w+av.w;
  *(float4*)&out[(size_t)r*DD + c4*4] = o;
}

// K5: P = AGG_seg @ W1 + b1 (MFMA); per-block BN partials -> global (NO atomics).
__global__ __launch_bounds__(256) void k5_gemm(
    const float* __restrict__ AGG4, const u16* __restrict__ W1swz,
    const float* __restrict__ b1, float* __restrict__ Px, float* __restrict__ Py,
    float* __restrict__ partial, int N)
{
  __shared__ __align__(16) u16 As[64*STRA];
  __shared__ __align__(16) float Cs[64*STRCF];
  const int tid = threadIdx.x;
  const int seg = blockIdx.y;
  const int soff = seg ? 256 : 0;
  const int r0 = blockIdx.x * 64;
  #pragma unroll
  for (int i = 0; i < 8; ++i) {
    int f = tid + 256*i;
    int row = f >> 5, c4 = f & 31;
    int r = r0 + row;
    float4 v = make_float4(0.f,0.f,0.f,0.f);
    if (r < N) v = *(const float4*)&AGG4[(size_t)r*512 + soff + c4*4];
    bf16x4 a;
    a.x = (short)f2bf(v.x); a.y = (short)f2bf(v.y);
    a.z = (short)f2bf(v.z); a.w = (short)f2bf(v.w);
    *(bf16x4*)&As[row*STRA + c4*4] = a;
  }
  __syncthreads();
  const int w = tid >> 6, l = tid & 63;
  const int m = l & 15, q = l >> 4;
  f32x4 acc[8];
  #pragma unroll
  for (int nt = 0; nt < 8; ++nt) acc[nt] = (f32x4){0.f,0.f,0.f,0.f};
  const int arow = w*16 + m;
  #pragma unroll
  for (int kt = 0; kt < 4; ++kt) {
    bf16x8 af = *(const bf16x8*)&As[arow*STRA + kt*32 + q*8];
    #pragma unroll
    for (int nt = 0; nt < 8; ++nt) {
      bf16x8 bf = *(const bf16x8*)(W1swz + ((size_t)(kt*8+nt)*64 + l)*8);
      acc[nt] = __builtin_amdgcn_mfma_f32_16x16x32_bf16(af, bf, acc[nt], 0, 0, 0);
    }
  }
  // bias (valid rows only) + per-wave column partials
  const int rbase = r0 + w*16 + q*4;
  float* red = Cs;    // scratch before C staging: [type][w*128 + col], 1024 floats
  #pragma unroll
  for (int nt = 0; nt < 8; ++nt) {
    float bv = b1[nt*16 + m];
    float sum = 0.f, sq = 0.f;
    #pragma unroll
    for (int i = 0; i < 4; ++i) {
      if (rbase + i < N) acc[nt][i] += bv; else acc[nt][i] = 0.f;
      sum += acc[nt][i]; sq += acc[nt][i]*acc[nt][i];
    }
    sum += __shfl_xor(sum, 16); sum += __shfl_xor(sum, 32);
    sq  += __shfl_xor(sq, 16);  sq  += __shfl_xor(sq, 32);
    if (l < 16) {
      red[      w*128 + nt*16 + l] = sum;
      red[512 + w*128 + nt*16 + l] = sq;
    }
  }
  __syncthreads();
  {
    int type = tid >> 7, col = tid & 127;
    float v = red[type*512 + col] + red[type*512 + 128 + col]
            + red[type*512 + 256 + col] + red[type*512 + 384 + col];
    partial[((size_t)seg*gridDim.x + blockIdx.x)*256 + tid] = v;
  }
  __syncthreads();
  #pragma unroll
  for (int nt = 0; nt < 8; ++nt)
    #pragma unroll
    for (int i = 0; i < 4; ++i)
      Cs[(w*16 + q*4 + i)*STRCF + nt*16 + m] = acc[nt][i];
  __syncthreads();
  const int ar = tid >> 2, p = tid & 3;
  const int r = r0 + ar;
  float* __restrict__ P = seg ? Py : Px;
  if (r < N) {
    const float* sp = &Cs[ar*STRCF + p*32];
    float* dp = &P[(size_t)r*DD + p*32];
    #pragma unroll
    for (int i = 0; i < 8; ++i)
      *(float4*)(dp + i*4) = *(const float4*)(sp + i*4);
  }
}

// K5b: reduce per-block partials into stats (few atomics).
__global__ __launch_bounds__(256) void k5b_stats(
    const float* __restrict__ partial, float* __restrict__ stats, int nb)
{
  int seg = blockIdx.y, chunk = blockIdx.x, t = threadIdx.x;
  int per = (nb + gridDim.x - 1) / gridDim.x;
  int lo = chunk*per, hi = lo+per; if (hi > nb) hi = nb;
  float s = 0.f;
  const float* p = partial + (size_t)seg*nb*256;
  for (int i = lo; i < hi; ++i) s += p[(size_t)i*256 + t];
  atomicAdd(&stats[seg*256 + t], s);
}

// K6: BN+PReLU -> MFMA GEMM2 (+b2) -> per-row BYOL cosine -> one atomic per block.
__global__ __launch_bounds__(256) void k6_gemm_loss(
    const float* __restrict__ Px, const float* __restrict__ Py,
    const float* __restrict__ AGG4, const float* __restrict__ stats,
    const float* __restrict__ gamma, const float* __restrict__ beta,
    const float* __restrict__ aP, const u16* __restrict__ W2swz,
    const float* __restrict__ b2, float* __restrict__ gloss, int N)
{
  __shared__ __align__(16) u16 As[64*STRA];
  __shared__ __align__(16) float Cs[64*STRCF];
  __shared__ float s1s[128], s2s[128];
  __shared__ float gred[4];
  const int tid = threadIdx.x;
  const int seg = blockIdx.y;
  const float* __restrict__ P = seg ? Py : Px;
  const int toff = seg ? 128 : 384;
  const float invN = 1.f / (float)N;
  if (tid < 128) {
    float mu = stats[seg*256 + tid] * invN;
    float var = stats[seg*256 + 128 + tid] * invN - mu*mu;
    float rstd = rsqrtf(var + 1e-5f);
    float s1 = rstd * gamma[tid];
    s1s[tid] = s1;
    s2s[tid] = beta[tid] - mu*s1;
  }
  const float alpha = aP[0];
  const int r0 = blockIdx.x * 64;
  __syncthreads();
  #pragma unroll
  for (int i = 0; i < 8; ++i) {
    int f = tid + 256*i;
    int row = f >> 5, c4 = f & 31;
    int r = r0 + row;
    float4 v = make_float4(0.f,0.f,0.f,0.f);
    if (r < N) v = *(const float4*)&P[(size_t)r*DD + c4*4];
    float h0 = v.x*s1s[c4*4+0] + s2s[c4*4+0];
    float h1 = v.y*s1s[c4*4+1] + s2s[c4*4+1];
    float h2 = v.z*s1s[c4*4+2] + s2s[c4*4+2];
    float h3 = v.w*s1s[c4*4+3] + s2s[c4*4+3];
    h0 = h0 >= 0.f ? h0 : alpha*h0;  h1 = h1 >= 0.f ? h1 : alpha*h1;
    h2 = h2 >= 0.f ? h2 : alpha*h2;  h3 = h3 >= 0.f ? h3 : alpha*h3;
    bf16x4 a;
    a.x = (short)f2bf(h0); a.y = (short)f2bf(h1);
    a.z = (short)f2bf(h2); a.w = (short)f2bf(h3);
    *(bf16x4*)&As[row*STRA + c4*4] = a;
  }
  __syncthreads();
  const int w = tid >> 6, l = tid & 63;
  const int m = l & 15, q = l >> 4;
  f32x4 acc[8];
  #pragma unroll
  for (int nt = 0; nt < 8; ++nt) acc[nt] = (f32x4){0.f,0.f,0.f,0.f};
  const int arow = w*16 + m;
  #pragma unroll
  for (int kt = 0; kt < 4; ++kt) {
    bf16x8 af = *(const bf16x8*)&As[arow*STRA + kt*32 + q*8];
    #pragma unroll
    for (int nt = 0; nt < 8; ++nt) {
      bf16x8 bf = *(const bf16x8*)(W2swz + ((size_t)(kt*8+nt)*64 + l)*8);
      acc[nt] = __builtin_amdgcn_mfma_f32_16x16x32_bf16(af, bf, acc[nt], 0, 0, 0);
    }
  }
  #pragma unroll
  for (int nt = 0; nt < 8; ++nt) {
    float bv = b2[nt*16 + m];
    #pragma unroll
    for (int i = 0; i < 4; ++i)
      Cs[(w*16 + q*4 + i)*STRCF + nt*16 + m] = acc[nt][i] + bv;
  }
  __syncthreads();
  float lsum = 0.f;
  for (int rr = 0; rr < 16; ++rr) {
    int ar = w*16 + rr;
    int r = r0 + ar;
    if (r >= N) break;   // uniform within wave
    float2 pv = *(const float2*)&Cs[ar*STRCF + l*2];
    float2 tv = *(const float2*)&AGG4[(size_t)r*512 + toff + l*2];
    float pp = pv.x*pv.x + pv.y*pv.y;
    float tt = tv.x*tv.x + tv.y*tv.y;
    float pt = pv.x*tv.x + pv.y*tv.y;
    #pragma unroll
    for (int off = 1; off <= 32; off <<= 1) {
      pp += __shfl_xor(pp, off);
      tt += __shfl_xor(tt, off);
      pt += __shfl_xor(pt, off);
    }
    if (l == 0) lsum += 2.f - 2.f * pt * rsqrtf(pp * tt);
  }
  if (l == 0) gred[w] = lsum;
  __syncthreads();
  if (tid == 0) atomicAdd(gloss, gred[0]+gred[1]+gred[2]+gred[3]);
}

__global__ void k7_loss(const float* __restrict__ gloss, float* __restrict__ out, int N, int total)
{
  out[total] = gloss[0] / (float)N;
}

extern "C" void kernel_launch(void* const* d_in, const int* in_sizes, int n_in,
                              void* d_out, int out_size, void* d_ws, size_t ws_size,
                              hipStream_t stream)
{
  const float* x    = (const float*)d_in[0];
  const float* perb = (const float*)d_in[1];
  const int*   erow = (const int*)d_in[2];
  const int*   ecol = (const int*)d_in[3];
  const float* eval_= (const float*)d_in[4];
  const float* W    = (const float*)d_in[5];
  const float* b    = (const float*)d_in[6];
  const float* Wt   = (const float*)d_in[7];
  const float* bt   = (const float*)d_in[8];
  const float* W1   = (const float*)d_in[9];
  const float* b1   = (const float*)d_in[10];
  const float* gam  = (const float*)d_in[11];
  const float* bet  = (const float*)d_in[12];
  const float* aP   = (const float*)d_in[13];
  const float* W2   = (const float*)d_in[14];
  const float* b2   = (const float*)d_in[15];
  const int N = in_sizes[0] / DD;
  const int E = in_sizes[2];
  const int NB5 = (N + 63)/64;

  char* ws = (char*)d_ws;
  size_t off = 0;
  auto alloc = [&](size_t bytes) -> void* {
    void* p = ws + off;
    off += (bytes + 255) & ~(size_t)255;
    return p;
  };
  float* AGG4 = (float*)alloc((size_t)N*512*sizeof(float)); // 102.4 MB
  u16*   H2   = (u16*)  alloc((size_t)N*512*sizeof(u16));   // 51.2 MB (reused as Px/Py)
  size_t zoff = off;                                        // ---- zeroed region ----
  int*   deg  = (int*)  alloc((size_t)N*sizeof(int));
  float* stats= (float*)alloc(512*sizeof(float));
  float* gloss= (float*)alloc(256);
  int*   ovfc = (int*)((char*)gloss + 64);
  size_t zbytes = off - zoff;                               // ---- end zeroed ----
  int*   perm = (int*)  alloc((size_t)N*CAP*sizeof(int));   // 19.2 MB
  int*   ovf  = (int*)  alloc(4096*sizeof(int));
  u16*   Bswz = (u16*)  alloc(32768*sizeof(u16));
  u16*   W1swz= (u16*)  alloc(16384*sizeof(u16));
  u16*   W2swz= (u16*)  alloc(16384*sizeof(u16));
  float* partial = (float*)alloc((size_t)2*NB5*256*sizeof(float)); // 1.6 MB
  if (ws_size < off) return;

  float* Px = (float*)H2;            // H2 dead after k3b
  float* Py = Px + (size_t)N*DD;

  hipMemsetAsync(ws + zoff, 0, zbytes, stream);
  k0_swz<<<256, 256, 0, stream>>>(W, Wt, W1, W2, Bswz, W1swz, W2swz);
  k1_gemm<<<(N + 31)/32, 256, 0, stream>>>(x, perb, Bswz, H2, N);
  k2_bucket<<<(E + 255)/256, 256, 0, stream>>>(erow, E, deg, perm, ovfc, ovf);
  k3_spmm<<<(N + 3)/4, 256, 0, stream>>>(ecol, eval_, deg, perm, H2, b, bt, AGG4, N);
  k3b_ovf<<<1, 256, 0, stream>>>(erow, ecol, eval_, ovfc, ovf, H2, AGG4);
  k4_embed<<<(N*32 + 255)/256, 256, 0, stream>>>(x, perb, AGG4, (float*)d_out, N*32);
  k5_gemm<<<dim3(NB5, 2), 256, 0, stream>>>(AGG4, W1swz, b1, Px, Py, partial, N);
  k5b_stats<<<dim3(16, 2), 256, 0, stream>>>(partial, stats, NB5);
  k6_gemm_loss<<<dim3(NB5, 2), 256, 0, stream>>>(Px, Py, AGG4, stats, gam, bet, aP, W2swz, b2, gloss, N);
  k7_loss<<<1, 1, 0, stream>>>(gloss, (float*)d_out, N, N*DD);
}

// Round 5
// 437.543 us; speedup vs baseline: 2.0873x; 1.1130x over previous
//
#include <hip/hip_runtime.h>
#include <stdint.h>

typedef unsigned short u16;
typedef unsigned int u32;
typedef __attribute__((ext_vector_type(8))) short bf16x8;
typedef __attribute__((ext_vector_type(4))) short bf16x4;
typedef __attribute__((ext_vector_type(4))) float f32x4;

#define DD 128
#define CAP 96
#define STRA 136   // A-tile LDS stride (u16): 272B rows, 16B-aligned
#define STRC1 264  // k1 C-tile stride (u16)
#define STRCF 132  // k5/k6 C-tile stride (f32)

__device__ __forceinline__ float bflo(u32 u){ return __uint_as_float(u<<16); }
__device__ __forceinline__ float bfhi(u32 u){ return __uint_as_float(u & 0xffff0000u); }
__device__ __forceinline__ float bf2f(u16 u){ return __uint_as_float(((u32)u)<<16); }
__device__ __forceinline__ u16 f2bf(float f){
  u32 u = __float_as_uint(f);
  return (u16)((u + 0x7fffu + ((u>>16)&1u)) >> 16);   // RNE
}

#define FMA8(hv, vj) do { \
    acc[0] += (vj)*bflo((hv).x); acc[1] += (vj)*bfhi((hv).x); \
    acc[2] += (vj)*bflo((hv).y); acc[3] += (vj)*bfhi((hv).y); \
    acc[4] += (vj)*bflo((hv).z); acc[5] += (vj)*bfhi((hv).z); \
    acc[6] += (vj)*bflo((hv).w); acc[7] += (vj)*bfhi((hv).w); } while(0)

// K0: pre-swizzle weights into MFMA B-fragment order.
__global__ __launch_bounds__(256) void k0_swz(
    const float* __restrict__ W, const float* __restrict__ Wt,
    const float* __restrict__ W1, const float* __restrict__ W2,
    u16* __restrict__ Bswz, u16* __restrict__ W1swz, u16* __restrict__ W2swz)
{
  int idx = blockIdx.x*256 + threadIdx.x;
  if (idx < 32768) {
    int j = idx & 7, lane = (idx>>3)&63, nt = (idx>>9)&15, kt = idx>>13;
    int k = kt*32 + (lane>>4)*8 + j, n = nt*16 + (lane&15);
    float v = (n < DD) ? W[k*DD + n] : Wt[k*DD + (n-DD)];
    Bswz[idx] = f2bf(v);
  } else {
    int t = idx - 32768;
    int which = t >> 14; t &= 16383;
    int j = t & 7, lane = (t>>3)&63, nt = (t>>9)&7, kt = (t>>12)&3;
    int k = kt*32 + (lane>>4)*8 + j, n = nt*16 + (lane&15);
    const float* __restrict__ src = which ? W2 : W1;
    u16* __restrict__ dst = which ? W2swz : W1swz;
    dst[t] = f2bf(src[k*DD + n]);
  }
}

// K1: MFMA GEMM. A-rows 0-31 = bf16(x), 32-63 = bf16(x+perb). B = [W|Wt].
// H2[2r] = [h1|ht1](r), H2[2r+1] = [h2|ht2](r).
__global__ __launch_bounds__(256) void k1_gemm(
    const float* __restrict__ x, const float* __restrict__ perb,
    const u16* __restrict__ Bswz, u16* __restrict__ H2, int N)
{
  __shared__ __align__(16) u16 As[64*STRA];
  __shared__ __align__(16) u16 Cs[64*STRC1];
  const int tid = threadIdx.x;
  const int r0 = blockIdx.x * 32;
  #pragma unroll
  for (int i = 0; i < 4; ++i) {
    int f = tid + 256*i;
    int row = f >> 5, c4 = f & 31;
    int r = r0 + row;
    float4 xv = make_float4(0.f,0.f,0.f,0.f), pv = xv;
    if (r < N) {
      xv = *(const float4*)&x[(size_t)r*DD + c4*4];
      pv = *(const float4*)&perb[(size_t)r*DD + c4*4];
    }
    bf16x4 a, s;
    a.x = (short)f2bf(xv.x); a.y = (short)f2bf(xv.y);
    a.z = (short)f2bf(xv.z); a.w = (short)f2bf(xv.w);
    s.x = (short)f2bf(xv.x+pv.x); s.y = (short)f2bf(xv.y+pv.y);
    s.z = (short)f2bf(xv.z+pv.z); s.w = (short)f2bf(xv.w+pv.w);
    *(bf16x4*)&As[row*STRA + c4*4]      = a;
    *(bf16x4*)&As[(32+row)*STRA + c4*4] = s;
  }
  __syncthreads();
  const int w = tid >> 6, l = tid & 63;
  const int m = l & 15, q = l >> 4;
  f32x4 acc[16];
  #pragma unroll
  for (int nt = 0; nt < 16; ++nt) acc[nt] = (f32x4){0.f,0.f,0.f,0.f};
  const int arow = w*16 + m;
  #pragma unroll
  for (int kt = 0; kt < 4; ++kt) {
    bf16x8 af = *(const bf16x8*)&As[arow*STRA + kt*32 + q*8];
    #pragma unroll
    for (int nt = 0; nt < 16; ++nt) {
      bf16x8 bf = *(const bf16x8*)(Bswz + ((size_t)(kt*16+nt)*64 + l)*8);
      acc[nt] = __builtin_amdgcn_mfma_f32_16x16x32_bf16(af, bf, acc[nt], 0, 0, 0);
    }
  }
  #pragma unroll
  for (int nt = 0; nt < 16; ++nt)
    #pragma unroll
    for (int i = 0; i < 4; ++i)
      Cs[(w*16 + q*4 + i)*STRC1 + nt*16 + m] = f2bf(acc[nt][i]);
  __syncthreads();
  const int ar = tid >> 2, p = tid & 3;
  const int src = r0 + (ar & 31);
  if (src < N) {
    size_t grow = (size_t)src*2 + (ar >> 5);
    const u16* sp = &Cs[ar*STRC1 + p*64];
    u16* dp = H2 + grow*256 + p*64;
    #pragma unroll
    for (int i = 0; i < 8; ++i)
      *(bf16x8*)(dp + i*8) = *(const bf16x8*)(sp + i*8);
  }
}

// K2: bucket edges by destination row, storing packed (col, val).
__global__ __launch_bounds__(256) void k2_bucket(
    const int* __restrict__ row, const int* __restrict__ col,
    const float* __restrict__ val, int E, int* __restrict__ deg,
    int2* __restrict__ perm, int* __restrict__ ovfc, int* __restrict__ ovf)
{
  int e = blockIdx.x*256 + threadIdx.x;
  if (e >= E) return;
  int r = row[e];
  int slot = atomicAdd(&deg[r], 1);
  if (slot < CAP) {
    int2 cv; cv.x = col[e]; cv.y = __float_as_int(val[e]);
    perm[(size_t)r*CAP + slot] = cv;
  }
  else { int oi = atomicAdd(ovfc, 1); if (oi < 4096) ovf[oi] = e; }
}

// K3: one wave per row; 4x-unrolled gather; bias fused; AGG written bf16;
// embed (= x+perb+agg2+b) written fp32 directly from registers (k4 fused).
__global__ __launch_bounds__(256) void k3_spmm(
    const int2* __restrict__ perm, const int* __restrict__ deg,
    const u16* __restrict__ H2, const float* __restrict__ b, const float* __restrict__ bt,
    const float* __restrict__ x, const float* __restrict__ perb,
    u16* __restrict__ AGGb, float* __restrict__ outE, int N)
{
  int row = blockIdx.x*4 + (threadIdx.x >> 6);
  int lane = threadIdx.x & 63;
  if (row >= N) return;
  int dg = deg[row]; if (dg > CAP) dg = CAP;
  float acc[8] = {0.f,0.f,0.f,0.f,0.f,0.f,0.f,0.f};
  const int boff = lane*8;
  for (int base = 0; base < dg; base += 64) {
    int2 ev = make_int2(0, 0);
    if (base + lane < dg) ev = perm[(size_t)row*CAP + base + lane];
    int c = ev.x; float v = __int_as_float(ev.y);
    int mm = dg - base; if (mm > 64) mm = 64;
    int j = 0;
    for (; j + 4 <= mm; j += 4) {
      int   c0 = __shfl(c, j),   c1 = __shfl(c, j+1);
      int   c2 = __shfl(c, j+2), c3 = __shfl(c, j+3);
      float v0 = __shfl(v, j),   v1 = __shfl(v, j+1);
      float v2 = __shfl(v, j+2), v3 = __shfl(v, j+3);
      uint4 h0 = *(const uint4*)(H2 + (size_t)c0*512 + boff);
      uint4 h1 = *(const uint4*)(H2 + (size_t)c1*512 + boff);
      uint4 h2 = *(const uint4*)(H2 + (size_t)c2*512 + boff);
      uint4 h3 = *(const uint4*)(H2 + (size_t)c3*512 + boff);
      FMA8(h0, v0); FMA8(h1, v1); FMA8(h2, v2); FMA8(h3, v3);
    }
    for (; j < mm; ++j) {
      int   cj = __shfl(c, j);
      float vj = __shfl(v, j);
      uint4 hv = *(const uint4*)(H2 + (size_t)cj*512 + boff);
      FMA8(hv, vj);
    }
  }
  const float* __restrict__ bp = (((lane>>4)&1)==0) ? b : bt;
  int d0 = (lane & 15) * 8;
  float o[8];
  #pragma unroll
  for (int i = 0; i < 8; ++i) o[i] = acc[i] + bp[d0+i];
  bf16x8 ob;
  #pragma unroll
  for (int i = 0; i < 8; ++i) ob[i] = (short)f2bf(o[i]);
  *(bf16x8*)(AGGb + (size_t)row*512 + boff) = ob;
  if ((lane >> 4) == 2) {   // lanes 32..47 hold seg2 = agg(h2)+b -> embed
    const float* xr = x    + (size_t)row*DD + d0;
    const float* pr = perb + (size_t)row*DD + d0;
    float4 xa = *(const float4*)xr, xb4 = *(const float4*)(xr+4);
    float4 pa = *(const float4*)pr, pb4 = *(const float4*)(pr+4);
    float4 e0, e1;
    e0.x = xa.x+pa.x+o[0]; e0.y = xa.y+pa.y+o[1];
    e0.z = xa.z+pa.z+o[2]; e0.w = xa.w+pa.w+o[3];
    e1.x = xb4.x+pb4.x+o[4]; e1.y = xb4.y+pb4.y+o[5];
    e1.z = xb4.z+pb4.z+o[6]; e1.w = xb4.w+pb4.w+o[7];
    float* er = outE + (size_t)row*DD + d0;
    *(float4*)er = e0;
    *(float4*)(er+4) = e1;
  }
}

// K3b: overflow fallback (expected empty) — serial single-block RMW fixup.
__global__ __launch_bounds__(256) void k3b_ovf(
    const int* __restrict__ rowI, const int* __restrict__ colI,
    const float* __restrict__ val, const int* __restrict__ ovfc,
    const int* __restrict__ ovf, const u16* __restrict__ H2,
    u16* __restrict__ AGGb, float* __restrict__ outE)
{
  int n = *ovfc; if (n > 4096) n = 4096;
  for (int i = 0; i < n; ++i) {
    int e = ovf[i];
    int r = rowI[e], c = colI[e];
    float v = val[e];
    for (int d = threadIdx.x; d < 512; d += 256) {
      float h = v * bf2f(H2[(size_t)c*512 + d]);
      u16* p = &AGGb[(size_t)r*512 + d];
      *p = f2bf(bf2f(*p) + h);
      if (d >= 256 && d < 384) {
        float* q = &outE[(size_t)r*DD + (d - 256)];
        *q = *q + h;
      }
    }
    __syncthreads();
  }
}

// K5: P = AGG_seg @ W1 + b1 (MFMA); per-block BN partials (no atomics); P stored bf16.
__global__ __launch_bounds__(256) void k5_gemm(
    const u16* __restrict__ AGGb, const u16* __restrict__ W1swz,
    const float* __restrict__ b1, u16* __restrict__ Px, u16* __restrict__ Py,
    float* __restrict__ partial, int N)
{
  __shared__ __align__(16) u16 As[64*STRA];
  __shared__ __align__(16) float Cs[64*STRCF];
  const int tid = threadIdx.x;
  const int seg = blockIdx.y;
  const int soff = seg ? 256 : 0;   // seg0 (online_x) or seg2 (online_y)
  const int r0 = blockIdx.x * 64;
  #pragma unroll
  for (int i = 0; i < 4; ++i) {
    int f = tid + 256*i;            // 1024 chunks: 64 rows x 16 chunks of 8 u16
    int row = f >> 4, c8 = f & 15;
    int r = r0 + row;
    bf16x8 ch = {0,0,0,0,0,0,0,0};
    if (r < N) ch = *(const bf16x8*)(AGGb + (size_t)r*512 + soff + c8*8);
    *(bf16x8*)&As[row*STRA + c8*8] = ch;
  }
  __syncthreads();
  const int w = tid >> 6, l = tid & 63;
  const int m = l & 15, q = l >> 4;
  f32x4 acc[8];
  #pragma unroll
  for (int nt = 0; nt < 8; ++nt) acc[nt] = (f32x4){0.f,0.f,0.f,0.f};
  const int arow = w*16 + m;
  #pragma unroll
  for (int kt = 0; kt < 4; ++kt) {
    bf16x8 af = *(const bf16x8*)&As[arow*STRA + kt*32 + q*8];
    #pragma unroll
    for (int nt = 0; nt < 8; ++nt) {
      bf16x8 bf = *(const bf16x8*)(W1swz + ((size_t)(kt*8+nt)*64 + l)*8);
      acc[nt] = __builtin_amdgcn_mfma_f32_16x16x32_bf16(af, bf, acc[nt], 0, 0, 0);
    }
  }
  const int rbase = r0 + w*16 + q*4;
  float* red = Cs;    // scratch: [type][wave*128 + col]
  #pragma unroll
  for (int nt = 0; nt < 8; ++nt) {
    float bv = b1[nt*16 + m];
    float sum = 0.f, sq = 0.f;
    #pragma unroll
    for (int i = 0; i < 4; ++i) {
      if (rbase + i < N) acc[nt][i] += bv; else acc[nt][i] = 0.f;
      sum += acc[nt][i]; sq += acc[nt][i]*acc[nt][i];
    }
    sum += __shfl_xor(sum, 16); sum += __shfl_xor(sum, 32);
    sq  += __shfl_xor(sq, 16);  sq  += __shfl_xor(sq, 32);
    if (l < 16) {
      red[      w*128 + nt*16 + l] = sum;
      red[512 + w*128 + nt*16 + l] = sq;
    }
  }
  __syncthreads();
  {
    int type = tid >> 7, col = tid & 127;
    float v = red[type*512 + col] + red[type*512 + 128 + col]
            + red[type*512 + 256 + col] + red[type*512 + 384 + col];
    partial[((size_t)seg*gridDim.x + blockIdx.x)*256 + tid] = v;
  }
  __syncthreads();
  #pragma unroll
  for (int nt = 0; nt < 8; ++nt)
    #pragma unroll
    for (int i = 0; i < 4; ++i)
      Cs[(w*16 + q*4 + i)*STRCF + nt*16 + m] = acc[nt][i];
  __syncthreads();
  const int ar = tid >> 2, p = tid & 3;
  const int r = r0 + ar;
  u16* __restrict__ P = seg ? Py : Px;
  if (r < N) {
    const float* sp = &Cs[ar*STRCF + p*32];
    u16* dp = P + (size_t)r*DD + p*32;
    #pragma unroll
    for (int i = 0; i < 4; ++i) {
      bf16x8 ob;
      #pragma unroll
      for (int t2 = 0; t2 < 8; ++t2) ob[t2] = (short)f2bf(sp[i*8+t2]);
      *(bf16x8*)(dp + i*8) = ob;
    }
  }
}

// K5b: reduce per-block partials into stats (few atomics).
__global__ __launch_bounds__(256) void k5b_stats(
    const float* __restrict__ partial, float* __restrict__ stats, int nb)
{
  int seg = blockIdx.y, chunk = blockIdx.x, t = threadIdx.x;
  int per = (nb + gridDim.x - 1) / gridDim.x;
  int lo = chunk*per, hi = lo+per; if (hi > nb) hi = nb;
  float s = 0.f;
  const float* p = partial + (size_t)seg*nb*256;
  for (int i = lo; i < hi; ++i) s += p[(size_t)i*256 + t];
  atomicAdd(&stats[seg*256 + t], s);
}

// K6: BN+PReLU (bf16 P) -> MFMA GEMM2 (+b2) -> per-row BYOL cosine (bf16 targets)
//     -> one atomic per block.
__global__ __launch_bounds__(256) void k6_gemm_loss(
    const u16* __restrict__ Px, const u16* __restrict__ Py,
    const u16* __restrict__ AGGb, const float* __restrict__ stats,
    const float* __restrict__ gamma, const float* __restrict__ beta,
    const float* __restrict__ aP, const u16* __restrict__ W2swz,
    const float* __restrict__ b2, float* __restrict__ gloss, int N)
{
  __shared__ __align__(16) u16 As[64*STRA];
  __shared__ __align__(16) float Cs[64*STRCF];
  __shared__ float s1s[128], s2s[128];
  __shared__ float gred[4];
  const int tid = threadIdx.x;
  const int seg = blockIdx.y;
  const u16* __restrict__ P = seg ? Py : Px;
  const int toff = seg ? 128 : 384;  // seg0: target_x = s3; seg1: target_y = s1
  const float invN = 1.f / (float)N;
  if (tid < 128) {
    float mu = stats[seg*256 + tid] * invN;
    float var = stats[seg*256 + 128 + tid] * invN - mu*mu;
    float rstd = rsqrtf(var + 1e-5f);
    float s1 = rstd * gamma[tid];
    s1s[tid] = s1;
    s2s[tid] = beta[tid] - mu*s1;
  }
  const float alpha = aP[0];
  const int r0 = blockIdx.x * 64;
  __syncthreads();
  #pragma unroll
  for (int i = 0; i < 4; ++i) {
    int f = tid + 256*i;
    int row = f >> 4, c8 = f & 15;
    int r = r0 + row;
    bf16x8 ch = {0,0,0,0,0,0,0,0};
    if (r < N) ch = *(const bf16x8*)(P + (size_t)r*DD + c8*8);
    bf16x8 a;
    #pragma unroll
    for (int t2 = 0; t2 < 8; ++t2) {
      int colc = c8*8 + t2;
      float hv = bf2f((u16)ch[t2]);
      float hn = hv*s1s[colc] + s2s[colc];
      hn = hn >= 0.f ? hn : alpha*hn;
      a[t2] = (short)f2bf(hn);
    }
    *(bf16x8*)&As[row*STRA + c8*8] = a;
  }
  __syncthreads();
  const int w = tid >> 6, l = tid & 63;
  const int m = l & 15, q = l >> 4;
  f32x4 acc[8];
  #pragma unroll
  for (int nt = 0; nt < 8; ++nt) acc[nt] = (f32x4){0.f,0.f,0.f,0.f};
  const int arow = w*16 + m;
  #pragma unroll
  for (int kt = 0; kt < 4; ++kt) {
    bf16x8 af = *(const bf16x8*)&As[arow*STRA + kt*32 + q*8];
    #pragma unroll
    for (int nt = 0; nt < 8; ++nt) {
      bf16x8 bf = *(const bf16x8*)(W2swz + ((size_t)(kt*8+nt)*64 + l)*8);
      acc[nt] = __builtin_amdgcn_mfma_f32_16x16x32_bf16(af, bf, acc[nt], 0, 0, 0);
    }
  }
  #pragma unroll
  for (int nt = 0; nt < 8; ++nt) {
    float bv = b2[nt*16 + m];
    #pragma unroll
    for (int i = 0; i < 4; ++i)
      Cs[(w*16 + q*4 + i)*STRCF + nt*16 + m] = acc[nt][i] + bv;
  }
  __syncthreads();
  float lsum = 0.f;
  for (int rr = 0; rr < 16; ++rr) {
    int ar = w*16 + rr;
    int r = r0 + ar;
    if (r >= N) break;   // uniform within wave
    float2 pv = *(const float2*)&Cs[ar*STRCF + l*2];
    u32 tw = *(const u32*)(AGGb + (size_t)r*512 + toff + l*2);
    float t0 = bflo(tw), t1 = bfhi(tw);
    float pp = pv.x*pv.x + pv.y*pv.y;
    float tt = t0*t0 + t1*t1;
    float pt = pv.x*t0 + pv.y*t1;
    #pragma unroll
    for (int off = 1; off <= 32; off <<= 1) {
      pp += __shfl_xor(pp, off);
      tt += __shfl_xor(tt, off);
      pt += __shfl_xor(pt, off);
    }
    if (l == 0) lsum += 2.f - 2.f * pt * rsqrtf(pp * tt);
  }
  if (l == 0) gred[w] = lsum;
  __syncthreads();
  if (tid == 0) atomicAdd(gloss, gred[0]+gred[1]+gred[2]+gred[3]);
}

__global__ void k7_loss(const float* __restrict__ gloss, float* __restrict__ out, int N, int total)
{
  out[total] = gloss[0] / (float)N;
}

extern "C" void kernel_launch(void* const* d_in, const int* in_sizes, int n_in,
                              void* d_out, int out_size, void* d_ws, size_t ws_size,
                              hipStream_t stream)
{
  const float* x    = (const float*)d_in[0];
  const float* perb = (const float*)d_in[1];
  const int*   erow = (const int*)d_in[2];
  const int*   ecol = (const int*)d_in[3];
  const float* eval_= (const float*)d_in[4];
  const float* W    = (const float*)d_in[5];
  const float* b    = (const float*)d_in[6];
  const float* Wt   = (const float*)d_in[7];
  const float* bt   = (const float*)d_in[8];
  const float* W1   = (const float*)d_in[9];
  const float* b1   = (const float*)d_in[10];
  const float* gam  = (const float*)d_in[11];
  const float* bet  = (const float*)d_in[12];
  const float* aP   = (const float*)d_in[13];
  const float* W2   = (const float*)d_in[14];
  const float* b2   = (const float*)d_in[15];
  const int N = in_sizes[0] / DD;
  const int E = in_sizes[2];
  const int NB5 = (N + 63)/64;

  char* ws = (char*)d_ws;
  size_t off = 0;
  auto alloc = [&](size_t bytes) -> void* {
    void* p = ws + off;
    off += (bytes + 255) & ~(size_t)255;
    return p;
  };
  u16*   AGGb = (u16*)  alloc((size_t)N*512*sizeof(u16));   // 51.2 MB (bf16)
  u16*   H2   = (u16*)  alloc((size_t)N*512*sizeof(u16));   // 51.2 MB (reused as Px/Py)
  size_t zoff = off;                                        // ---- zeroed region ----
  int*   deg  = (int*)  alloc((size_t)N*sizeof(int));
  float* stats= (float*)alloc(512*sizeof(float));
  float* gloss= (float*)alloc(256);
  int*   ovfc = (int*)((char*)gloss + 64);
  size_t zbytes = off - zoff;                               // ---- end zeroed ----
  int2*  perm = (int2*) alloc((size_t)N*CAP*sizeof(int2));  // 38.4 MB
  int*   ovf  = (int*)  alloc(4096*sizeof(int));
  u16*   Bswz = (u16*)  alloc(32768*sizeof(u16));
  u16*   W1swz= (u16*)  alloc(16384*sizeof(u16));
  u16*   W2swz= (u16*)  alloc(16384*sizeof(u16));
  float* partial = (float*)alloc((size_t)2*NB5*256*sizeof(float)); // 1.6 MB
  if (ws_size < off) return;

  u16* Px = H2;                      // H2 dead after k3b; 2 x 12.8 MB bf16
  u16* Py = Px + (size_t)N*DD;

  hipMemsetAsync(ws + zoff, 0, zbytes, stream);
  k0_swz<<<256, 256, 0, stream>>>(W, Wt, W1, W2, Bswz, W1swz, W2swz);
  k1_gemm<<<(N + 31)/32, 256, 0, stream>>>(x, perb, Bswz, H2, N);
  k2_bucket<<<(E + 255)/256, 256, 0, stream>>>(erow, ecol, eval_, E, deg, perm, ovfc, ovf);
  k3_spmm<<<(N + 3)/4, 256, 0, stream>>>(perm, deg, H2, b, bt, x, perb, AGGb, (float*)d_out, N);
  k3b_ovf<<<1, 256, 0, stream>>>(erow, ecol, eval_, ovfc, ovf, H2, AGGb, (float*)d_out);
  k5_gemm<<<dim3(NB5, 2), 256, 0, stream>>>(AGGb, W1swz, b1, Px, Py, partial, N);
  k5b_stats<<<dim3(16, 2), 256, 0, stream>>>(partial, stats, NB5);
  k6_gemm_loss<<<dim3(NB5, 2), 256, 0, stream>>>(Px, Py, AGGb, stats, gam, bet, aP, W2swz, b2, gloss, N);
  k7_loss<<<1, 1, 0, stream>>>(gloss, (float*)d_out, N, N*DD);
}

// Round 7
// 365.615 us; speedup vs baseline: 2.4979x; 1.1967x over previous
//
#include <hip/hip_runtime.h>
#include <stdint.h>

typedef unsigned short u16;
typedef unsigned int u32;
typedef __attribute__((ext_vector_type(8))) short bf16x8;
typedef __attribute__((ext_vector_type(4))) short bf16x4;
typedef __attribute__((ext_vector_type(4))) float f32x4;

#define DD 128
#define CAP 96
#define STRA 136   // A-tile LDS stride (u16): 272B rows, 16B-aligned
#define STRC1 264  // C-tile stride (u16)
#define STRCF 132  // k5/k6 C-tile stride (f32)

__device__ __forceinline__ float bflo(u32 u){ return __uint_as_float(u<<16); }
__device__ __forceinline__ float bfhi(u32 u){ return __uint_as_float(u & 0xffff0000u); }
__device__ __forceinline__ float bf2f(u16 u){ return __uint_as_float(((u32)u)<<16); }
__device__ __forceinline__ u16 f2bf(float f){
  u32 u = __float_as_uint(f);
  return (u16)((u + 0x7fffu + ((u>>16)&1u)) >> 16);   // RNE
}

#define FMA4(hv, vj) do { \
    acc[0] += (vj)*bflo((hv).x); acc[1] += (vj)*bfhi((hv).x); \
    acc[2] += (vj)*bflo((hv).y); acc[3] += (vj)*bfhi((hv).y); } while(0)

// KZ: zero the control region via a COMPUTE kernel (never SDMA/memset-node —
// guarantees serial ordering inside the captured graph; hipMemsetAsync's
// memset node was the R6 replay-divergence culprit).
__global__ __launch_bounds__(256) void kZ_zero(
    int* __restrict__ deg, float* __restrict__ stats,
    float* __restrict__ gbuf, int N)
{
  int i = blockIdx.x*256 + threadIdx.x;
  if (i < N) deg[i] = 0;
  if (i < 512) stats[i] = 0.f;
  if (i < 64) gbuf[i] = 0.f;   // covers gloss + ovfc (256B block)
}

// K0: pre-swizzle weights into MFMA B-fragment order. Bswz = [W|Wt] (256 cols).
__global__ __launch_bounds__(256) void k0_swz(
    const float* __restrict__ W, const float* __restrict__ Wt,
    const float* __restrict__ W1, const float* __restrict__ W2,
    u16* __restrict__ Bswz, u16* __restrict__ W1swz, u16* __restrict__ W2swz)
{
  int idx = blockIdx.x*256 + threadIdx.x;
  if (idx < 32768) {
    int j = idx & 7, lane = (idx>>3)&63, nt = (idx>>9)&15, kt = idx>>13;
    int k = kt*32 + (lane>>4)*8 + j, n = nt*16 + (lane&15);
    float v = (n < DD) ? W[k*DD + n] : Wt[k*DD + (n-DD)];
    Bswz[idx] = f2bf(v);
  } else {
    int t = idx - 32768;
    int which = t >> 14; t &= 16383;
    int j = t & 7, lane = (t>>3)&63, nt = (t>>9)&7, kt = (t>>12)&3;
    int k = kt*32 + (lane>>4)*8 + j, n = nt*16 + (lane&15);
    const float* __restrict__ src = which ? W2 : W1;
    u16* __restrict__ dst = which ? W2swz : W1swz;
    dst[t] = f2bf(src[k*DD + n]);
  }
}

// KT: gather table T[r] = [bf16(x_r) (128) | bf16(perb_r) (128)].
__global__ __launch_bounds__(256) void kT_build(
    const float* __restrict__ x, const float* __restrict__ perb,
    u16* __restrict__ T, int nchunks)
{
  int f = blockIdx.x*256 + threadIdx.x;   // 8-elem chunks: N*32
  if (f >= nchunks) return;
  int r = f >> 5, c8 = f & 31;
  const float* src = (c8 < 16) ? (x + (size_t)r*DD + c8*8)
                               : (perb + (size_t)r*DD + (c8-16)*8);
  float4 a = *(const float4*)src;
  float4 bq = *(const float4*)(src + 4);
  bf16x8 o;
  o[0]=(short)f2bf(a.x); o[1]=(short)f2bf(a.y); o[2]=(short)f2bf(a.z); o[3]=(short)f2bf(a.w);
  o[4]=(short)f2bf(bq.x); o[5]=(short)f2bf(bq.y); o[6]=(short)f2bf(bq.z); o[7]=(short)f2bf(bq.w);
  *(bf16x8*)(T + (size_t)r*256 + c8*8) = o;
}

// K2: bucket edges by destination row, storing packed (col, val).
__global__ __launch_bounds__(256) void k2_bucket(
    const int* __restrict__ row, const int* __restrict__ col,
    const float* __restrict__ val, int E, int* __restrict__ deg,
    int2* __restrict__ perm, int* __restrict__ ovfc, int* __restrict__ ovf)
{
  int e = blockIdx.x*256 + threadIdx.x;
  if (e >= E) return;
  int r = row[e];
  int slot = atomicAdd(&deg[r], 1);
  if (slot < CAP) {
    int2 cv; cv.x = col[e]; cv.y = __float_as_int(val[e]);
    perm[(size_t)r*CAP + slot] = cv;
  }
  else { int oi = atomicAdd(ovfc, 1); if (oi < 4096) ovf[oi] = e; }
}

// K3: one wave per row; gather 512B/edge from T; 4x unrolled.
// Output T2[r] = [aggx1 (128) | aggx2=aggx1+aggp (128)] bf16 (no bias).
__global__ __launch_bounds__(256) void k3_spmm(
    const int2* __restrict__ perm, const int* __restrict__ deg,
    const u16* __restrict__ T, u16* __restrict__ T2, int N)
{
  int row = blockIdx.x*4 + (threadIdx.x >> 6);
  int lane = threadIdx.x & 63;
  if (row >= N) return;
  int dg = deg[row];
  dg = dg < 0 ? 0 : (dg > CAP ? CAP : dg);       // defensive clamp
  float acc[4] = {0.f,0.f,0.f,0.f};
  const int boff = lane*4;   // elem offset in 256-wide T row (8B/lane)
  for (int base = 0; base < dg; base += 64) {
    int2 ev = make_int2(0, 0);
    if (base + lane < dg) ev = perm[(size_t)row*CAP + base + lane];
    int c = ev.x; float v = __int_as_float(ev.y);
    c = ((unsigned)c < (unsigned)N) ? c : 0;     // defensive clamp (no wild OOB)
    int mm = dg - base; if (mm > 64) mm = 64;
    int j = 0;
    for (; j + 4 <= mm; j += 4) {
      int   c0 = __shfl(c, j),   c1 = __shfl(c, j+1);
      int   c2 = __shfl(c, j+2), c3 = __shfl(c, j+3);
      float v0 = __shfl(v, j),   v1 = __shfl(v, j+1);
      float v2 = __shfl(v, j+2), v3 = __shfl(v, j+3);
      uint2 h0 = *(const uint2*)(T + (size_t)c0*256 + boff);
      uint2 h1 = *(const uint2*)(T + (size_t)c1*256 + boff);
      uint2 h2 = *(const uint2*)(T + (size_t)c2*256 + boff);
      uint2 h3 = *(const uint2*)(T + (size_t)c3*256 + boff);
      FMA4(h0, v0); FMA4(h1, v1); FMA4(h2, v2); FMA4(h3, v3);
    }
    for (; j < mm; ++j) {
      int   cj = __shfl(c, j);
      float vj = __shfl(v, j);
      uint2 hv = *(const uint2*)(T + (size_t)cj*256 + boff);
      FMA4(hv, vj);
    }
  }
  // lanes 0-31 hold aggx1 elems, lanes 32-63 hold aggp elems (same elem idx).
  bf16x4 ob;
  #pragma unroll
  for (int i = 0; i < 4; ++i) {
    float xpart = __shfl(acc[i], lane & 31);   // aggx1 elem from partner lane
    float o = (lane < 32) ? acc[i] : (xpart + acc[i]);   // aggx1 | aggx2
    ob[i] = (short)f2bf(o);
  }
  *(bf16x4*)(T2 + (size_t)row*256 + lane*4) = ob;
}

// K3b: overflow fallback (expected empty) — serial RMW on T2.
__global__ __launch_bounds__(256) void k3b_ovf(
    const int* __restrict__ rowI, const int* __restrict__ colI,
    const float* __restrict__ val, const int* __restrict__ ovfc,
    const int* __restrict__ ovf, const u16* __restrict__ T,
    u16* __restrict__ T2)
{
  int n = *ovfc; if (n > 4096) n = 4096;
  for (int i = 0; i < n; ++i) {
    int e = ovf[i];
    int r = rowI[e], c = colI[e];
    float v = val[e];
    int d = threadIdx.x;           // 256 threads cover the 256-wide row
    int dl = d & 127;
    float add = v * bf2f(T[(size_t)c*256 + dl]);
    if (d >= 128) add += v * bf2f(T[(size_t)c*256 + 128 + dl]);
    u16* p = &T2[(size_t)r*256 + d];
    *p = f2bf(bf2f(*p) + add);
  }
}

// K4: dense MFMA GEMM [aggx1;aggx2] @ [W|Wt] + bias -> AGGb (bf16,
// AGGb[r] = [s0 s1 s2 s3]); embed = x+perb+s2 written fp32.
__global__ __launch_bounds__(256) void k4_gemm(
    const u16* __restrict__ T2, const u16* __restrict__ Bswz,
    const float* __restrict__ b, const float* __restrict__ bt,
    const float* __restrict__ x, const float* __restrict__ perb,
    u16* __restrict__ AGGb, float* __restrict__ outE, int N)
{
  __shared__ __align__(16) u16 As[64*STRA];
  __shared__ __align__(16) u16 Cs[64*STRC1];
  const int tid = threadIdx.x;
  const int r0 = blockIdx.x * 32;
  #pragma unroll
  for (int i = 0; i < 4; ++i) {
    int f = tid + 256*i;            // 1024 chunks: 64 A-rows x 16 chunks of 8
    int row = f >> 4, c8 = f & 15;
    int r = r0 + (row & 31);
    bf16x8 ch = {0,0,0,0,0,0,0,0};
    if (r < N) ch = *(const bf16x8*)(T2 + (size_t)r*256 + (row>>5)*128 + c8*8);
    *(bf16x8*)&As[row*STRA + c8*8] = ch;
  }
  __syncthreads();
  const int w = tid >> 6, l = tid & 63;
  const int m = l & 15, q = l >> 4;
  f32x4 acc[16];
  #pragma unroll
  for (int nt = 0; nt < 16; ++nt) acc[nt] = (f32x4){0.f,0.f,0.f,0.f};
  const int arow = w*16 + m;
  #pragma unroll
  for (int kt = 0; kt < 4; ++kt) {
    bf16x8 af = *(const bf16x8*)&As[arow*STRA + kt*32 + q*8];
    #pragma unroll
    for (int nt = 0; nt < 16; ++nt) {
      bf16x8 bf = *(const bf16x8*)(Bswz + ((size_t)(kt*16+nt)*64 + l)*8);
      acc[nt] = __builtin_amdgcn_mfma_f32_16x16x32_bf16(af, bf, acc[nt], 0, 0, 0);
    }
  }
  #pragma unroll
  for (int nt = 0; nt < 16; ++nt) {
    int n = nt*16 + m;
    float bv = (n < 128) ? b[n] : bt[n-128];
    #pragma unroll
    for (int i = 0; i < 4; ++i)
      Cs[(w*16 + q*4 + i)*STRC1 + nt*16 + m] = f2bf(acc[nt][i] + bv);
  }
  __syncthreads();
  {
    const int ar = tid >> 2, p = tid & 3;
    const int src = r0 + (ar & 31);
    if (src < N) {
      size_t grow = (size_t)src*2 + (ar >> 5);  // even: [s0|s1], odd: [s2|s3]
      const u16* sp = &Cs[ar*STRC1 + p*64];
      u16* dp = AGGb + grow*256 + p*64;
      #pragma unroll
      for (int i = 0; i < 8; ++i)
        *(bf16x8*)(dp + i*8) = *(const bf16x8*)(sp + i*8);
    }
  }
  // embed = x + perb + s2  (s2 = rows 32-63 of Cs, cols 0..127, bias included)
  #pragma unroll
  for (int i = 0; i < 2; ++i) {
    int f = tid + 256*i;            // 512 chunks: 32 rows x 16 chunks of 8
    int rr = f >> 4, c8 = f & 15;
    int src = r0 + rr;
    if (src < N) {
      const u16* cp = &Cs[(32+rr)*STRC1 + c8*8];
      const float* xr = x    + (size_t)src*DD + c8*8;
      const float* pr = perb + (size_t)src*DD + c8*8;
      float4 xa = *(const float4*)xr, xb4 = *(const float4*)(xr+4);
      float4 pa = *(const float4*)pr, pb4 = *(const float4*)(pr+4);
      float4 e0, e1;
      e0.x = xa.x+pa.x+bf2f(cp[0]); e0.y = xa.y+pa.y+bf2f(cp[1]);
      e0.z = xa.z+pa.z+bf2f(cp[2]); e0.w = xa.w+pa.w+bf2f(cp[3]);
      e1.x = xb4.x+pb4.x+bf2f(cp[4]); e1.y = xb4.y+pb4.y+bf2f(cp[5]);
      e1.z = xb4.z+pb4.z+bf2f(cp[6]); e1.w = xb4.w+pb4.w+bf2f(cp[7]);
      float* er = outE + (size_t)src*DD + c8*8;
      *(float4*)er = e0;
      *(float4*)(er+4) = e1;
    }
  }
}

// K5: P = AGG_seg @ W1 + b1 (MFMA); per-block BN partials (no atomics); P bf16.
__global__ __launch_bounds__(256) void k5_gemm(
    const u16* __restrict__ AGGb, const u16* __restrict__ W1swz,
    const float* __restrict__ b1, u16* __restrict__ Px, u16* __restrict__ Py,
    float* __restrict__ partial, int N)
{
  __shared__ __align__(16) u16 As[64*STRA];
  __shared__ __align__(16) float Cs[64*STRCF];
  const int tid = threadIdx.x;
  const int seg = blockIdx.y;
  const int soff = seg ? 256 : 0;   // seg0 (online_x) or seg2 (online_y)
  const int r0 = blockIdx.x * 64;
  #pragma unroll
  for (int i = 0; i < 4; ++i) {
    int f = tid + 256*i;
    int row = f >> 4, c8 = f & 15;
    int r = r0 + row;
    bf16x8 ch = {0,0,0,0,0,0,0,0};
    if (r < N) ch = *(const bf16x8*)(AGGb + (size_t)r*512 + soff + c8*8);
    *(bf16x8*)&As[row*STRA + c8*8] = ch;
  }
  __syncthreads();
  const int w = tid >> 6, l = tid & 63;
  const int m = l & 15, q = l >> 4;
  f32x4 acc[8];
  #pragma unroll
  for (int nt = 0; nt < 8; ++nt) acc[nt] = (f32x4){0.f,0.f,0.f,0.f};
  const int arow = w*16 + m;
  #pragma unroll
  for (int kt = 0; kt < 4; ++kt) {
    bf16x8 af = *(const bf16x8*)&As[arow*STRA + kt*32 + q*8];
    #pragma unroll
    for (int nt = 0; nt < 8; ++nt) {
      bf16x8 bf = *(const bf16x8*)(W1swz + ((size_t)(kt*8+nt)*64 + l)*8);
      acc[nt] = __builtin_amdgcn_mfma_f32_16x16x32_bf16(af, bf, acc[nt], 0, 0, 0);
    }
  }
  const int rbase = r0 + w*16 + q*4;
  float* red = Cs;    // scratch: [type][wave*128 + col]
  #pragma unroll
  for (int nt = 0; nt < 8; ++nt) {
    float bv = b1[nt*16 + m];
    float sum = 0.f, sq = 0.f;
    #pragma unroll
    for (int i = 0; i < 4; ++i) {
      if (rbase + i < N) acc[nt][i] += bv; else acc[nt][i] = 0.f;
      sum += acc[nt][i]; sq += acc[nt][i]*acc[nt][i];
    }
    sum += __shfl_xor(sum, 16); sum += __shfl_xor(sum, 32);
    sq  += __shfl_xor(sq, 16);  sq  += __shfl_xor(sq, 32);
    if (l < 16) {
      red[      w*128 + nt*16 + l] = sum;
      red[512 + w*128 + nt*16 + l] = sq;
    }
  }
  __syncthreads();
  {
    int type = tid >> 7, col = tid & 127;
    float v = red[type*512 + col] + red[type*512 + 128 + col]
            + red[type*512 + 256 + col] + red[type*512 + 384 + col];
    partial[((size_t)seg*gridDim.x + blockIdx.x)*256 + tid] = v;
  }
  __syncthreads();
  #pragma unroll
  for (int nt = 0; nt < 8; ++nt)
    #pragma unroll
    for (int i = 0; i < 4; ++i)
      Cs[(w*16 + q*4 + i)*STRCF + nt*16 + m] = acc[nt][i];
  __syncthreads();
  const int ar = tid >> 2, p = tid & 3;
  const int r = r0 + ar;
  u16* __restrict__ P = seg ? Py : Px;
  if (r < N) {
    const float* sp = &Cs[ar*STRCF + p*32];
    u16* dp = P + (size_t)r*DD + p*32;
    #pragma unroll
    for (int i = 0; i < 4; ++i) {
      bf16x8 ob;
      #pragma unroll
      for (int t2 = 0; t2 < 8; ++t2) ob[t2] = (short)f2bf(sp[i*8+t2]);
      *(bf16x8*)(dp + i*8) = ob;
    }
  }
}

// K5b: reduce per-block partials into stats (few atomics).
__global__ __launch_bounds__(256) void k5b_stats(
    const float* __restrict__ partial, float* __restrict__ stats, int nb)
{
  int seg = blockIdx.y, chunk = blockIdx.x, t = threadIdx.x;
  int per = (nb + gridDim.x - 1) / gridDim.x;
  int lo = chunk*per, hi = lo+per; if (hi > nb) hi = nb;
  float s = 0.f;
  const float* p = partial + (size_t)seg*nb*256;
  for (int i = lo; i < hi; ++i) s += p[(size_t)i*256 + t];
  atomicAdd(&stats[seg*256 + t], s);
}

// K6: BN+PReLU (bf16 P) -> MFMA GEMM2 (+b2) -> per-row BYOL cosine -> 1 atomic/block.
__global__ __launch_bounds__(256) void k6_gemm_loss(
    const u16* __restrict__ Px, const u16* __restrict__ Py,
    const u16* __restrict__ AGGb, const float* __restrict__ stats,
    const float* __restrict__ gamma, const float* __restrict__ beta,
    const float* __restrict__ aP, const u16* __restrict__ W2swz,
    const float* __restrict__ b2, float* __restrict__ gloss, int N)
{
  __shared__ __align__(16) u16 As[64*STRA];
  __shared__ __align__(16) float Cs[64*STRCF];
  __shared__ float s1s[128], s2s[128];
  __shared__ float gred[4];
  const int tid = threadIdx.x;
  const int seg = blockIdx.y;
  const u16* __restrict__ P = seg ? Py : Px;
  const int toff = seg ? 128 : 384;  // seg0: target_x = s3; seg1: target_y = s1
  const float invN = 1.f / (float)N;
  if (tid < 128) {
    float mu = stats[seg*256 + tid] * invN;
    float var = stats[seg*256 + 128 + tid] * invN - mu*mu;
    float rstd = rsqrtf(var + 1e-5f);
    float s1 = rstd * gamma[tid];
    s1s[tid] = s1;
    s2s[tid] = beta[tid] - mu*s1;
  }
  const float alpha = aP[0];
  const int r0 = blockIdx.x * 64;
  __syncthreads();
  #pragma unroll
  for (int i = 0; i < 4; ++i) {
    int f = tid + 256*i;
    int row = f >> 4, c8 = f & 15;
    int r = r0 + row;
    bf16x8 ch = {0,0,0,0,0,0,0,0};
    if (r < N) ch = *(const bf16x8*)(P + (size_t)r*DD + c8*8);
    bf16x8 a;
    #pragma unroll
    for (int t2 = 0; t2 < 8; ++t2) {
      int colc = c8*8 + t2;
      float hv = bf2f((u16)ch[t2]);
      float hn = hv*s1s[colc] + s2s[colc];
      hn = hn >= 0.f ? hn : alpha*hn;
      a[t2] = (short)f2bf(hn);
    }
    *(bf16x8*)&As[row*STRA + c8*8] = a;
  }
  __syncthreads();
  const int w = tid >> 6, l = tid & 63;
  const int m = l & 15, q = l >> 4;
  f32x4 acc[8];
  #pragma unroll
  for (int nt = 0; nt < 8; ++nt) acc[nt] = (f32x4){0.f,0.f,0.f,0.f};
  const int arow = w*16 + m;
  #pragma unroll
  for (int kt = 0; kt < 4; ++kt) {
    bf16x8 af = *(const bf16x8*)&As[arow*STRA + kt*32 + q*8];
    #pragma unroll
    for (int nt = 0; nt < 8; ++nt) {
      bf16x8 bf = *(const bf16x8*)(W2swz + ((size_t)(kt*8+nt)*64 + l)*8);
      acc[nt] = __builtin_amdgcn_mfma_f32_16x16x32_bf16(af, bf, acc[nt], 0, 0, 0);
    }
  }
  #pragma unroll
  for (int nt = 0; nt < 8; ++nt) {
    float bv = b2[nt*16 + m];
    #pragma unroll
    for (int i = 0; i < 4; ++i)
      Cs[(w*16 + q*4 + i)*STRCF + nt*16 + m] = acc[nt][i] + bv;
  }
  __syncthreads();
  float lsum = 0.f;
  for (int rr = 0; rr < 16; ++rr) {
    int ar = w*16 + rr;
    int r = r0 + ar;
    if (r >= N) break;   // uniform within wave
    float2 pv = *(const float2*)&Cs[ar*STRCF + l*2];
    u32 tw = *(const u32*)(AGGb + (size_t)r*512 + toff + l*2);
    float t0 = bflo(tw), t1 = bfhi(tw);
    float pp = pv.x*pv.x + pv.y*pv.y;
    float tt = t0*t0 + t1*t1;
    float pt = pv.x*t0 + pv.y*t1;
    #pragma unroll
    for (int off = 1; off <= 32; off <<= 1) {
      pp += __shfl_xor(pp, off);
      tt += __shfl_xor(tt, off);
      pt += __shfl_xor(pt, off);
    }
    if (l == 0) lsum += 2.f - 2.f * pt * rsqrtf(pp * tt);
  }
  if (l == 0) gred[w] = lsum;
  __syncthreads();
  if (tid == 0) atomicAdd(gloss, gred[0]+gred[1]+gred[2]+gred[3]);
}

__global__ void k7_loss(const float* __restrict__ gloss, float* __restrict__ out, int N, int total)
{
  out[total] = gloss[0] / (float)N;
}

extern "C" void kernel_launch(void* const* d_in, const int* in_sizes, int n_in,
                              void* d_out, int out_size, void* d_ws, size_t ws_size,
                              hipStream_t stream)
{
  const float* x    = (const float*)d_in[0];
  const float* perb = (const float*)d_in[1];
  const int*   erow = (const int*)d_in[2];
  const int*   ecol = (const int*)d_in[3];
  const float* eval_= (const float*)d_in[4];
  const float* W    = (const float*)d_in[5];
  const float* b    = (const float*)d_in[6];
  const float* Wt   = (const float*)d_in[7];
  const float* bt   = (const float*)d_in[8];
  const float* W1   = (const float*)d_in[9];
  const float* b1   = (const float*)d_in[10];
  const float* gam  = (const float*)d_in[11];
  const float* bet  = (const float*)d_in[12];
  const float* aP   = (const float*)d_in[13];
  const float* W2   = (const float*)d_in[14];
  const float* b2   = (const float*)d_in[15];
  const int N = in_sizes[0] / DD;
  const int E = in_sizes[2];
  const int NB5 = (N + 63)/64;

  char* ws = (char*)d_ws;
  size_t off = 0;
  auto alloc = [&](size_t bytes) -> void* {
    void* p = ws + off;
    off += (bytes + 255) & ~(size_t)255;
    return p;
  };
  u16*   AGGb = (u16*)  alloc((size_t)N*512*sizeof(u16));   // 51.2 MB (bf16)
  u16*   T    = (u16*)  alloc((size_t)N*256*sizeof(u16));   // 25.6 MB (reused as Px/Py)
  u16*   T2   = (u16*)  alloc((size_t)N*256*sizeof(u16));   // 25.6 MB
  int*   deg  = (int*)  alloc((size_t)N*sizeof(int));
  float* stats= (float*)alloc(512*sizeof(float));
  float* gloss= (float*)alloc(256);
  int*   ovfc = (int*)((char*)gloss + 64);
  int2*  perm = (int2*) alloc((size_t)N*CAP*sizeof(int2));  // 38.4 MB
  int*   ovf  = (int*)  alloc(4096*sizeof(int));
  u16*   Bswz = (u16*)  alloc(32768*sizeof(u16));
  u16*   W1swz= (u16*)  alloc(16384*sizeof(u16));
  u16*   W2swz= (u16*)  alloc(16384*sizeof(u16));
  float* partial = (float*)alloc((size_t)2*NB5*256*sizeof(float)); // 1.6 MB
  if (ws_size < off) return;

  u16* Px = T;                       // T dead after k4; 2 x 12.8 MB bf16
  u16* Py = Px + (size_t)N*DD;

  kZ_zero<<<(N + 255)/256, 256, 0, stream>>>(deg, stats, gloss, N);
  k0_swz<<<256, 256, 0, stream>>>(W, Wt, W1, W2, Bswz, W1swz, W2swz);
  kT_build<<<(N*32 + 255)/256, 256, 0, stream>>>(x, perb, T, N*32);
  k2_bucket<<<(E + 255)/256, 256, 0, stream>>>(erow, ecol, eval_, E, deg, perm, ovfc, ovf);
  k3_spmm<<<(N + 3)/4, 256, 0, stream>>>(perm, deg, T, T2, N);
  k3b_ovf<<<1, 256, 0, stream>>>(erow, ecol, eval_, ovfc, ovf, T, T2);
  k4_gemm<<<(N + 31)/32, 256, 0, stream>>>(T2, Bswz, b, bt, x, perb, AGGb, (float*)d_out, N);
  k5_gemm<<<dim3(NB5, 2), 256, 0, stream>>>(AGGb, W1swz, b1, Px, Py, partial, N);
  k5b_stats<<<dim3(16, 2), 256, 0, stream>>>(partial, stats, NB5);
  k6_gemm_loss<<<dim3(NB5, 2), 256, 0, stream>>>(Px, Py, AGGb, stats, gam, bet, aP, W2swz, b2, gloss, N);
  k7_loss<<<1, 1, 0, stream>>>(gloss, (float*)d_out, N, N*DD);
}